// Round 3
// baseline (372.239 us; speedup 1.0000x reference)
//
#include <hip/hip_runtime.h>
#include <hip/hip_bf16.h>
#include <cstdint>

// ---------------------------------------------------------------------------
// MAB block: Qp=(Q@Wq+bq)*Qm; Kp=(K@Wk+bk)*Km; V=K@Wv+bv
// S = Qh Kh^T / sqrt(512);  X = exp(exp(S)*Km)*Qm;  A = X/(sum+1e-8)
// O = Qh + A@Vh;  O = LN0(O);  O = O + relu(O@Wo+bo);  out = LN1(O)
//
// R2 post-mortem: NaN with finite-bf16-proof math ==> inputs are float32
// (reference is jnp.float32; f32 read as bf16 yields NaN bit patterns).
// This version DETECTS dtype at runtime (flag in ws) and handles both:
//   - detect_dtype: f32 N(0,1) dwords are in [1e-8,1e4]; bf16-packed are not.
//   - convert_all: weights/biases/gains/masks -> bf16 scratch.
//   - gemm512: A staged from raw ptr per dtype (f32: float4+cvt; bf16: async).
//   - internal pipeline all-bf16 (structure identical to R1).
//   - lnorm_out: final store f32 or bf16 per flag.
// ws: flags + cW(2MB) + T(2MB) + smalls + masks + Qp(16MB) + Kp(16MB) ~ 37.8MB
// d_out doubles as V scratch (>=16MB under either out dtype; dead before LN1).
// ---------------------------------------------------------------------------

typedef __bf16 bf16;
typedef __bf16 bf16x8 __attribute__((ext_vector_type(8)));
typedef float f32x4 __attribute__((ext_vector_type(4)));

#define MFMA16(a, b, c) __builtin_amdgcn_mfma_f32_16x16x32_bf16((a), (b), (c), 0, 0, 0)

static __device__ __forceinline__ void async_lds16(const bf16* g, bf16* l) {
  __builtin_amdgcn_global_load_lds(
      (__attribute__((address_space(1))) void*)(void*)g,
      (__attribute__((address_space(3))) void*)l,
      16, 0, 0);
}

// ---------------------------------------------------------------------------
// Dtype detection: flags[0]=1 if f32 inputs, 0 if bf16. flags[1]=0 always.
// ---------------------------------------------------------------------------
__global__ __launch_bounds__(256) void detect_dtype(
    const unsigned* __restrict__ q, int* __restrict__ flags) {
  __shared__ int cnt;
  if (threadIdx.x == 0) cnt = 0;
  __syncthreads();
  const float f = __uint_as_float(q[threadIdx.x]);
  const float a = fabsf(f);
  if (a > 1e-8f && a < 1e4f) atomicAdd(&cnt, 1);
  __syncthreads();
  if (threadIdx.x == 0) {
    flags[0] = (cnt >= 200) ? 1 : 0;
    flags[1] = 0;
  }
}

// ---------------------------------------------------------------------------
// Batched conversion of 14 small/medium arrays to bf16 (or copy if already).
// ---------------------------------------------------------------------------
struct ConvArgs {
  const void* src[14];
  bf16* dst[14];
  int n[14];
};

__global__ __launch_bounds__(256) void convert_all(ConvArgs a, const int* flags) {
  const int seg = blockIdx.z;
  const int n = a.n[seg];
  const long i = ((long)blockIdx.x * 256 + threadIdx.x) * 8;
  if (i >= n) return;
  bf16* d = a.dst[seg];
  if (flags[0]) {
    const float* s = (const float*)a.src[seg];
    const f32x4 x0 = *(const f32x4*)(s + i);
    const f32x4 x1 = *(const f32x4*)(s + i + 4);
    bf16x8 o;
#pragma unroll
    for (int j = 0; j < 4; ++j) { o[j] = (bf16)x0[j]; o[j + 4] = (bf16)x1[j]; }
    *(bf16x8*)(d + i) = o;
  } else {
    *(bf16x8*)(d + i) = *(const bf16x8*)((const bf16*)a.src[seg] + i);
  }
}

// ---------------------------------------------------------------------------
// Weight transpose: Wt[n][k] = W[k][n], 512x512 bf16 (from converted weights).
// ---------------------------------------------------------------------------
__global__ __launch_bounds__(256) void transpose512(
    const bf16* __restrict__ Wq, const bf16* __restrict__ Wk,
    const bf16* __restrict__ Wv, const bf16* __restrict__ Wo,
    bf16* __restrict__ Tq, bf16* __restrict__ Tk,
    bf16* __restrict__ Tv, bf16* __restrict__ To) {
  const bf16* src;
  bf16* dst;
  switch (blockIdx.z) {
    case 0: src = Wq; dst = Tq; break;
    case 1: src = Wk; dst = Tk; break;
    case 2: src = Wv; dst = Tv; break;
    default: src = Wo; dst = To; break;
  }
  __shared__ bf16 t[32][33];
  const int tx = threadIdx.x;          // 0..31
  const int ty = threadIdx.y;          // 0..7
  const int n0 = blockIdx.x * 32;
  const int k0 = blockIdx.y * 32;
#pragma unroll
  for (int j = 0; j < 4; ++j)
    t[ty + j * 8][tx] = src[(k0 + ty + j * 8) * 512 + n0 + tx];
  __syncthreads();
#pragma unroll
  for (int j = 0; j < 4; ++j)
    dst[(size_t)(n0 + ty + j * 8) * 512 + k0 + tx] = t[tx][ty + j * 8];
}

// ---------------------------------------------------------------------------
// GEMM: out[M x 512] = epilogue(A[M x 512] @ Bt^T + bias), A dtype per flag.
//   Bt [512 n][512 k] bf16.  mask: row mask.  resid: FFN relu+residual.
// m97 structure: 128x128 tile, BK=32, 4 waves.
// ---------------------------------------------------------------------------
__global__ __launch_bounds__(256) void gemm512(
    const void* __restrict__ A, const bf16* __restrict__ Bt,
    const bf16* __restrict__ bias, const bf16* __restrict__ mask,
    const bf16* __restrict__ resid, bf16* __restrict__ out,
    const int* __restrict__ flags) {
  __shared__ bf16 sA[128 * 32];
  __shared__ bf16 sB[128 * 32];
  const int isf32 = flags[0];
  const int tid = threadIdx.x;
  const int lane = tid & 63;
  const int w = tid >> 6;
  const int fm = lane & 15;
  const int fq = lane >> 4;
  const long rowBase = (long)blockIdx.y * 128;
  const int colBase = blockIdx.x * 128;

  f32x4 acc[4][4] = {};

  const int c0 = tid, c1 = tid + 256;
  const int r0 = c0 >> 2, o0 = (c0 & 3) * 8;
  const int r1 = c1 >> 2, o1 = (c1 & 3) * 8;
  const bf16* A0 = (const bf16*)A + (rowBase + r0) * 512 + o0;
  const bf16* A1 = (const bf16*)A + (rowBase + r1) * 512 + o1;
  const float* F0 = (const float*)A + (rowBase + r0) * 512 + o0;
  const float* F1 = (const float*)A + (rowBase + r1) * 512 + o1;
  const bf16* B0 = Bt + (size_t)(colBase + r0) * 512 + o0;
  const bf16* B1 = Bt + (size_t)(colBase + r1) * 512 + o1;

  const int wr = (w & 1) * 64;
  const int wc = (w >> 1) * 64;

  for (int kt = 0; kt < 16; ++kt) {
    __syncthreads();
    const int k0 = kt * 32;
    if (isf32) {
      const f32x4 x0 = *(const f32x4*)(F0 + k0);
      const f32x4 x1 = *(const f32x4*)(F0 + k0 + 4);
      const f32x4 y0 = *(const f32x4*)(F1 + k0);
      const f32x4 y1 = *(const f32x4*)(F1 + k0 + 4);
      bf16x8 p, q;
#pragma unroll
      for (int j = 0; j < 4; ++j) {
        p[j] = (bf16)x0[j]; p[j + 4] = (bf16)x1[j];
        q[j] = (bf16)y0[j]; q[j + 4] = (bf16)y1[j];
      }
      *(bf16x8*)(sA + c0 * 8) = p;
      *(bf16x8*)(sA + c1 * 8) = q;
    } else {
      async_lds16(A0 + k0, sA + c0 * 8);
      async_lds16(A1 + k0, sA + c1 * 8);
    }
    async_lds16(B0 + k0, sB + c0 * 8);
    async_lds16(B1 + k0, sB + c1 * 8);
    __syncthreads();
    bf16x8 a[4], b[4];
#pragma unroll
    for (int i = 0; i < 4; ++i)
      a[i] = *(const bf16x8*)(sA + (wr + i * 16 + fm) * 32 + fq * 8);
#pragma unroll
    for (int j = 0; j < 4; ++j)
      b[j] = *(const bf16x8*)(sB + (wc + j * 16 + fm) * 32 + fq * 8);
#pragma unroll
    for (int i = 0; i < 4; ++i)
#pragma unroll
      for (int j = 0; j < 4; ++j)
        acc[i][j] = MFMA16(a[i], b[j], acc[i][j]);
  }

  // epilogue; C/D layout: col = lane&15, row = (lane>>4)*4 + r
#pragma unroll
  for (int i = 0; i < 4; ++i) {
#pragma unroll
    for (int r = 0; r < 4; ++r) {
      const long R = rowBase + wr + i * 16 + fq * 4 + r;
      const float mk = mask ? (float)mask[R] : 1.0f;
      const bf16* resrow = resid ? resid + R * 512 : nullptr;
      bf16* outrow = out + R * 512;
#pragma unroll
      for (int j = 0; j < 4; ++j) {
        const int C = colBase + wc + j * 16 + fm;
        float v = acc[i][j][r] + (float)bias[C];
        if (mask) v *= mk;
        if (resid) v = (float)resrow[C] + fmaxf(v, 0.0f);
        outrow[C] = (bf16)v;
      }
    }
  }
}

// ---------------------------------------------------------------------------
// Attention: block per (q-tile 64, batch, head); all-bf16 internal.
// Writes O in-place over Qp (own tile staged to sQ before any store).
// ---------------------------------------------------------------------------
__global__ __launch_bounds__(256) void attn_kernel(
    bf16* __restrict__ Qp, const bf16* __restrict__ Kp,
    const bf16* __restrict__ Vv, const bf16* __restrict__ Qm,
    const bf16* __restrict__ Km) {
  __shared__ bf16 sQ[64][72];
  __shared__ bf16 sK[64][72];
  __shared__ bf16 sVt[64][72];
  __shared__ bf16 sX[4][16][72];
  __shared__ float sKm[64];

  const int tid = threadIdx.x;
  const int lane = tid & 63;
  const int w = tid >> 6;
  const int fm = lane & 15;
  const int fq = lane >> 4;
  const int q0 = blockIdx.x * 64;
  const int b = blockIdx.y;
  const int hh = blockIdx.z;

  bf16* Qbase = Qp + ((long)b * 1024 + q0) * 512 + hh * 64;
  for (int c = tid; c < 512; c += 256) {
    const int row = c >> 3, col = (c & 7) * 8;
    *(bf16x8*)(&sQ[row][col]) = *(const bf16x8*)(Qbase + (long)row * 512 + col);
  }
  float qm[4];
#pragma unroll
  for (int r = 0; r < 4; ++r)
    qm[r] = (float)Qm[(long)b * 1024 + q0 + w * 16 + fq * 4 + r];

  f32x4 acc_o[4] = {};
  float l_part[4] = {0.f, 0.f, 0.f, 0.f};
  const float scale = 0.04419417382415922f;  // 1/sqrt(512)

  for (int kt = 0; kt < 16; ++kt) {
    const int kk0 = kt * 64;
    __syncthreads();
    const bf16* Kbase = Kp + ((long)b * 1024 + kk0) * 512 + hh * 64;
    const bf16* Vbase = Vv + ((long)b * 1024 + kk0) * 512 + hh * 64;
    for (int c = tid; c < 512; c += 256) {
      const int row = c >> 3, col = (c & 7) * 8;
      *(bf16x8*)(&sK[row][col]) = *(const bf16x8*)(Kbase + (long)row * 512 + col);
    }
    {
      const int rp = tid >> 3;
      const int colb = (tid & 7) * 8;
      const int row = rp * 2;
      const bf16* vp = Vbase + (long)row * 512 + colb;
      bf16x8 v0 = *(const bf16x8*)vp;
      bf16x8 v1 = *(const bf16x8*)(vp + 512);
      const unsigned short* p0 = (const unsigned short*)&v0;
      const unsigned short* p1 = (const unsigned short*)&v1;
#pragma unroll
      for (int j = 0; j < 8; ++j) {
        const unsigned pk = (unsigned)p0[j] | ((unsigned)p1[j] << 16);
        *(unsigned*)((void*)&sVt[colb + j][row]) = pk;
      }
    }
    if (tid < 64) sKm[tid] = (float)Km[(long)b * 1024 + kk0 + tid];
    __syncthreads();

    f32x4 s_acc[4] = {};
#pragma unroll
    for (int ks = 0; ks < 2; ++ks) {
      const bf16x8 aq = *(const bf16x8*)(&sQ[w * 16 + fm][ks * 32 + fq * 8]);
#pragma unroll
      for (int t = 0; t < 4; ++t) {
        const bf16x8 bk = *(const bf16x8*)(&sK[t * 16 + fm][ks * 32 + fq * 8]);
        s_acc[t] = MFMA16(aq, bk, s_acc[t]);
      }
    }
#pragma unroll
    for (int t = 0; t < 4; ++t) {
      const float km = sKm[t * 16 + fm];
#pragma unroll
      for (int r = 0; r < 4; ++r) {
        const float s = s_acc[t][r] * scale;
        const float x = __expf(__expf(s) * km) * qm[r];
        l_part[r] += x;
        sX[w][fq * 4 + r][t * 16 + fm] = (bf16)x;
      }
    }
    __syncthreads();
#pragma unroll
    for (int ks = 0; ks < 2; ++ks) {
      const bf16x8 ax = *(const bf16x8*)(&sX[w][fm][ks * 32 + fq * 8]);
#pragma unroll
      for (int t = 0; t < 4; ++t) {
        const bf16x8 bv = *(const bf16x8*)(&sVt[t * 16 + fm][ks * 32 + fq * 8]);
        acc_o[t] = MFMA16(ax, bv, acc_o[t]);
      }
    }
  }

#pragma unroll
  for (int r = 0; r < 4; ++r) {
    float v = l_part[r];
    v += __shfl_xor(v, 1);
    v += __shfl_xor(v, 2);
    v += __shfl_xor(v, 4);
    v += __shfl_xor(v, 8);
    l_part[r] = v;
  }

#pragma unroll
  for (int t = 0; t < 4; ++t) {
#pragma unroll
    for (int r = 0; r < 4; ++r) {
      const int qr = w * 16 + fq * 4 + r;
      const int dc = t * 16 + fm;
      const float val = (float)sQ[qr][dc] + acc_o[t][r] / (l_part[r] + 1e-8f);
      Qbase[(long)qr * 512 + dc] = (bf16)val;
    }
  }
}

// ---------------------------------------------------------------------------
// LayerNorm (bf16 -> bf16). One wave per row. In-place safe.
// ---------------------------------------------------------------------------
__global__ __launch_bounds__(256) void lnorm(
    const bf16* __restrict__ X, const bf16* __restrict__ g,
    const bf16* __restrict__ bb, bf16* __restrict__ out) {
  const int row = blockIdx.x * 4 + (threadIdx.x >> 6);
  const int lane = threadIdx.x & 63;
  const bf16x8 v = *(const bf16x8*)(X + (size_t)row * 512 + lane * 8);
  float x[8], s = 0.f, ss = 0.f;
#pragma unroll
  for (int j = 0; j < 8; ++j) {
    x[j] = (float)v[j];
    s += x[j];
    ss += x[j] * x[j];
  }
#pragma unroll
  for (int m = 1; m < 64; m <<= 1) {
    s += __shfl_xor(s, m);
    ss += __shfl_xor(ss, m);
  }
  const float mean = s * (1.0f / 512.0f);
  const float var = ss * (1.0f / 512.0f) - mean * mean;
  const float rstd = 1.0f / sqrtf(var + 1e-5f);
  const bf16x8 gv = *(const bf16x8*)(g + lane * 8);
  const bf16x8 bv = *(const bf16x8*)(bb + lane * 8);
  bf16x8 o;
#pragma unroll
  for (int j = 0; j < 8; ++j)
    o[j] = (bf16)((x[j] - mean) * rstd * (float)gv[j] + (float)bv[j]);
  *(bf16x8*)(out + (size_t)row * 512 + lane * 8) = o;
}

// ---------------------------------------------------------------------------
// Final LayerNorm: bf16 in, out dtype per flag (f32 or bf16).
// ---------------------------------------------------------------------------
__global__ __launch_bounds__(256) void lnorm_out(
    const bf16* __restrict__ X, const bf16* __restrict__ g,
    const bf16* __restrict__ bb, void* __restrict__ out,
    const int* __restrict__ flags) {
  const int row = blockIdx.x * 4 + (threadIdx.x >> 6);
  const int lane = threadIdx.x & 63;
  const bf16x8 v = *(const bf16x8*)(X + (size_t)row * 512 + lane * 8);
  float x[8], s = 0.f, ss = 0.f;
#pragma unroll
  for (int j = 0; j < 8; ++j) {
    x[j] = (float)v[j];
    s += x[j];
    ss += x[j] * x[j];
  }
#pragma unroll
  for (int m = 1; m < 64; m <<= 1) {
    s += __shfl_xor(s, m);
    ss += __shfl_xor(ss, m);
  }
  const float mean = s * (1.0f / 512.0f);
  const float var = ss * (1.0f / 512.0f) - mean * mean;
  const float rstd = 1.0f / sqrtf(var + 1e-5f);
  const bf16x8 gv = *(const bf16x8*)(g + lane * 8);
  const bf16x8 bv = *(const bf16x8*)(bb + lane * 8);
  float o[8];
#pragma unroll
  for (int j = 0; j < 8; ++j)
    o[j] = (x[j] - mean) * rstd * (float)gv[j] + (float)bv[j];
  if (flags[0]) {
    float* fo = (float*)out + (size_t)row * 512 + lane * 8;
    f32x4 a, b;
#pragma unroll
    for (int j = 0; j < 4; ++j) { a[j] = o[j]; b[j] = o[j + 4]; }
    *(f32x4*)fo = a;
    *(f32x4*)(fo + 4) = b;
  } else {
    bf16x8 ob;
#pragma unroll
    for (int j = 0; j < 8; ++j) ob[j] = (bf16)o[j];
    *(bf16x8*)((bf16*)out + (size_t)row * 512 + lane * 8) = ob;
  }
}

// ---------------------------------------------------------------------------
extern "C" void kernel_launch(void* const* d_in, const int* in_sizes, int n_in,
                              void* d_out, int out_size, void* d_ws, size_t ws_size,
                              hipStream_t stream) {
  (void)in_sizes; (void)n_in; (void)out_size; (void)ws_size;
  const void* Q  = d_in[0];
  const void* K  = d_in[1];

  bf16* ws = (bf16*)d_ws;
  int* flags = (int*)d_ws;                 // 2 ints @ offset 0 (256B reserved)
  const long W2 = 512L * 512;
  const long MN = 16384L * 512;
  bf16* cWq = ws + 128;                    // 4 converted weights: 2MB
  bf16* cWk = cWq + W2;
  bf16* cWv = cWk + W2;
  bf16* cWo = cWv + W2;
  bf16* Tq = cWo + W2;                     // 4 transposed weights: 2MB
  bf16* Tk = Tq + W2;
  bf16* Tv = Tk + W2;
  bf16* To = Tv + W2;
  bf16* sm = To + W2;                      // 8 x 512 smalls (bq,bk,bv,bo,g0,b0,g1,b1)
  bf16* cQm = sm + 8 * 512;                // 16384
  bf16* cKm = cQm + 16384;                 // 16384
  bf16* Qp = cKm + 16384;                  // 16MB
  bf16* Kp = Qp + MN;                      // 16MB
  bf16* Vx = (bf16*)d_out;                 // V scratch in d_out (dead before LN1)

  bf16* cbq = sm + 0 * 512;
  bf16* cbk = sm + 1 * 512;
  bf16* cbv = sm + 2 * 512;
  bf16* cbo = sm + 3 * 512;
  bf16* cg0 = sm + 4 * 512;
  bf16* cb0 = sm + 5 * 512;
  bf16* cg1 = sm + 6 * 512;
  bf16* cb1 = sm + 7 * 512;

  detect_dtype<<<1, 256, 0, stream>>>((const unsigned*)Q, flags);

  ConvArgs ca;
  ca.src[0] = d_in[4];  ca.dst[0] = cWq;  ca.n[0] = 512 * 512;   // Wq
  ca.src[1] = d_in[6];  ca.dst[1] = cWk;  ca.n[1] = 512 * 512;   // Wk
  ca.src[2] = d_in[8];  ca.dst[2] = cWv;  ca.n[2] = 512 * 512;   // Wv
  ca.src[3] = d_in[10]; ca.dst[3] = cWo;  ca.n[3] = 512 * 512;   // Wo
  ca.src[4] = d_in[2];  ca.dst[4] = cQm;  ca.n[4] = 16384;       // Qm
  ca.src[5] = d_in[3];  ca.dst[5] = cKm;  ca.n[5] = 16384;       // Km
  ca.src[6] = d_in[5];  ca.dst[6] = cbq;  ca.n[6] = 512;         // bq
  ca.src[7] = d_in[7];  ca.dst[7] = cbk;  ca.n[7] = 512;         // bk
  ca.src[8] = d_in[9];  ca.dst[8] = cbv;  ca.n[8] = 512;         // bv
  ca.src[9] = d_in[11]; ca.dst[9] = cbo;  ca.n[9] = 512;         // bo
  ca.src[10] = d_in[12]; ca.dst[10] = cg0; ca.n[10] = 512;       // g0
  ca.src[11] = d_in[13]; ca.dst[11] = cb0; ca.n[11] = 512;       // b0
  ca.src[12] = d_in[14]; ca.dst[12] = cg1; ca.n[12] = 512;       // g1
  ca.src[13] = d_in[15]; ca.dst[13] = cb1; ca.n[13] = 512;       // b1
  convert_all<<<dim3(128, 1, 14), 256, 0, stream>>>(ca, flags);

  transpose512<<<dim3(16, 16, 4), dim3(32, 8), 0, stream>>>(
      cWq, cWk, cWv, cWo, Tq, Tk, Tv, To);

  const dim3 gg(4, 128);
  gemm512<<<gg, 256, 0, stream>>>(Q, Tq, cbq, cQm, nullptr, Qp, flags);
  gemm512<<<gg, 256, 0, stream>>>(K, Tk, cbk, cKm, nullptr, Kp, flags);
  gemm512<<<gg, 256, 0, stream>>>(K, Tv, cbv, nullptr, nullptr, Vx, flags);

  attn_kernel<<<dim3(16, 16, 8), 256, 0, stream>>>(Qp, Kp, Vx, cQm, cKm);

  lnorm<<<4096, 256, 0, stream>>>(Qp, cg0, cb0, Qp);
  gemm512<<<gg, 256, 0, stream>>>(Qp, To, cbo, nullptr, Qp, Kp, flags + 1);
  lnorm_out<<<4096, 256, 0, stream>>>(Kp, cg1, cb1, d_out, flags);
}

// Round 4
// 351.320 us; speedup vs baseline: 1.0595x; 1.0595x over previous
//
#include <hip/hip_runtime.h>
#include <hip/hip_bf16.h>
#include <cstdint>

// ---------------------------------------------------------------------------
// MAB block (f32 in/out, bf16 internal):
//   Qp=(Q@Wq+bq)*Qm; Kp=(K@Wk+bk)*Km; V=K@Wv+bv
//   S = Qh Kh^T / sqrt(512);  X = exp(exp(S)*Km)*Qm;  A = X/(sum+1e-8)
//   O = Qh + A@Vh;  O = LN0(O);  O = O + relu(O@Wo+bo);  out = LN1(O)
//
// R3 post-mortem: inputs/outputs proven f32 (R1 bf16-identical failed, R3
// runtime-flag passed). attn had 2.5e7 LDS bank conflicts (~30% of dur):
//   (a) in-kernel V transpose wrote 8-way-conflicted (stride 36 dw, 8x36==0
//       mod 32)  -> FIX: pre-transpose V in global (Vt in d_out upper 16MB).
//   (b) 16x scalar b16 sX writes (4-way) -> FIX: compute S^T (swap MFMA
//       operands) so each lane holds 4 consecutive kk -> 4x b64 writes.
// ws ~ 34MB: T(2MB) + smalls + masks + Qp(16MB) + Kp(16MB).
// ---------------------------------------------------------------------------

typedef __bf16 bf16;
typedef __bf16 bf16x4 __attribute__((ext_vector_type(4)));
typedef __bf16 bf16x8 __attribute__((ext_vector_type(8)));
typedef float f32x4 __attribute__((ext_vector_type(4)));

#define MFMA16(a, b, c) __builtin_amdgcn_mfma_f32_16x16x32_bf16((a), (b), (c), 0, 0, 0)

static __device__ __forceinline__ void async_lds16(const bf16* g, bf16* l) {
  __builtin_amdgcn_global_load_lds(
      (__attribute__((address_space(1))) void*)(void*)g,
      (__attribute__((address_space(3))) void*)l,
      16, 0, 0);
}

// ---------------------------------------------------------------------------
// Weight convert+transpose: T[n][k] = (bf16)W[k][n], 512x512, f32 in.
// 64x64 tiles; z selects matrix.
// ---------------------------------------------------------------------------
__global__ __launch_bounds__(256) void transposeW(
    const float* __restrict__ Wq, const float* __restrict__ Wk,
    const float* __restrict__ Wv, const float* __restrict__ Wo,
    bf16* __restrict__ Tq, bf16* __restrict__ Tk,
    bf16* __restrict__ Tv, bf16* __restrict__ To) {
  const float* src;
  bf16* dst;
  switch (blockIdx.z) {
    case 0: src = Wq; dst = Tq; break;
    case 1: src = Wk; dst = Tk; break;
    case 2: src = Wv; dst = Tv; break;
    default: src = Wo; dst = To; break;
  }
  __shared__ bf16 t[64][72];
  const int tid = threadIdx.x;
  const int n0 = blockIdx.x * 64;
  const int k0 = blockIdx.y * 64;
  for (int c = tid; c < 512; c += 256) {
    const int row = c >> 3, col = (c & 7) * 8;   // row: k, col: n
    const float* sp = src + (size_t)(k0 + row) * 512 + n0 + col;
    const f32x4 a = *(const f32x4*)sp;
    const f32x4 b = *(const f32x4*)(sp + 4);
    bf16x8 v;
#pragma unroll
    for (int j = 0; j < 4; ++j) { v[j] = (bf16)a[j]; v[j + 4] = (bf16)b[j]; }
    *(bf16x8*)(&t[row][col]) = v;
  }
  __syncthreads();
  for (int c = tid; c < 512; c += 256) {
    const int row = c >> 3, col8 = (c & 7) * 8;  // row: n, col8: k
    bf16x8 v;
#pragma unroll
    for (int j = 0; j < 8; ++j) v[j] = t[col8 + j][row];
    *(bf16x8*)(dst + (size_t)(n0 + row) * 512 + k0 + col8) = v;
  }
}

// ---------------------------------------------------------------------------
// Batched f32->bf16 conversion of 10 small arrays (masks, biases, gains).
// ---------------------------------------------------------------------------
struct ConvArgs {
  const float* src[10];
  bf16* dst[10];
  int n[10];
};

__global__ __launch_bounds__(256) void convert_all(ConvArgs a) {
  const int seg = blockIdx.z;
  const int n = a.n[seg];
  const long i = ((long)blockIdx.x * 256 + threadIdx.x) * 8;
  if (i >= n) return;
  const float* s = a.src[seg];
  const f32x4 x0 = *(const f32x4*)(s + i);
  const f32x4 x1 = *(const f32x4*)(s + i + 4);
  bf16x8 o;
#pragma unroll
  for (int j = 0; j < 4; ++j) { o[j] = (bf16)x0[j]; o[j + 4] = (bf16)x1[j]; }
  *(bf16x8*)(a.dst[seg] + i) = o;
}

// ---------------------------------------------------------------------------
// V transpose: Vt[(b*8+h)*64 + d][kk] = V[b][kk][h*64+d]. 64x64 tiles.
// d-tile == head (dh=64), so blockIdx.y is the head index.
// ---------------------------------------------------------------------------
__global__ __launch_bounds__(256) void transposeV(
    const bf16* __restrict__ V, bf16* __restrict__ Vt) {
  __shared__ bf16 t[64][72];
  const int tid = threadIdx.x;
  const int kk0 = blockIdx.x * 64;
  const int d0 = blockIdx.y * 64;
  const int b = blockIdx.z;
  const bf16* src = V + ((long)b * 1024 + kk0) * 512 + d0;
  for (int c = tid; c < 512; c += 256) {
    const int row = c >> 3, col = (c & 7) * 8;   // row: kk, col: d
    *(bf16x8*)(&t[row][col]) = *(const bf16x8*)(src + (long)row * 512 + col);
  }
  __syncthreads();
  bf16* dst = Vt + ((long)b * 8 + (d0 >> 6)) * 64 * 1024 + kk0;
  for (int c = tid; c < 512; c += 256) {
    const int drow = c >> 3, col8 = (c & 7) * 8; // drow: d, col8: kk
    bf16x8 v;
#pragma unroll
    for (int j = 0; j < 8; ++j) v[j] = t[col8 + j][drow];
    *(bf16x8*)(dst + (long)drow * 1024 + col8) = v;
  }
}

// ---------------------------------------------------------------------------
// GEMM: out[M x 512] = epilogue(A[M x 512] @ Bt^T + bias). A f32 or bf16.
//   mask != null : out = (acc+bias) * mask[row]
//   resid != null: out = resid + relu(acc+bias)
// m97 structure: 128x128 tile, BK=32, 4 waves.
// ---------------------------------------------------------------------------
template <bool AF32>
__global__ __launch_bounds__(256) void gemm512(
    const void* __restrict__ A, const bf16* __restrict__ Bt,
    const bf16* __restrict__ bias, const bf16* __restrict__ mask,
    const bf16* __restrict__ resid, bf16* __restrict__ out) {
  __shared__ bf16 sA[128 * 32];
  __shared__ bf16 sB[128 * 32];
  const int tid = threadIdx.x;
  const int lane = tid & 63;
  const int w = tid >> 6;
  const int fm = lane & 15;
  const int fq = lane >> 4;
  const long rowBase = (long)blockIdx.y * 128;
  const int colBase = blockIdx.x * 128;

  f32x4 acc[4][4] = {};

  const int c0 = tid, c1 = tid + 256;
  const int r0 = c0 >> 2, o0 = (c0 & 3) * 8;
  const int r1 = c1 >> 2, o1 = (c1 & 3) * 8;
  const bf16* A0 = (const bf16*)A + (rowBase + r0) * 512 + o0;
  const bf16* A1 = (const bf16*)A + (rowBase + r1) * 512 + o1;
  const float* F0 = (const float*)A + (rowBase + r0) * 512 + o0;
  const float* F1 = (const float*)A + (rowBase + r1) * 512 + o1;
  const bf16* B0 = Bt + (size_t)(colBase + r0) * 512 + o0;
  const bf16* B1 = Bt + (size_t)(colBase + r1) * 512 + o1;

  const int wr = (w & 1) * 64;
  const int wc = (w >> 1) * 64;

  for (int kt = 0; kt < 16; ++kt) {
    __syncthreads();
    const int k0 = kt * 32;
    if (AF32) {
      const f32x4 x0 = *(const f32x4*)(F0 + k0);
      const f32x4 x1 = *(const f32x4*)(F0 + k0 + 4);
      const f32x4 y0 = *(const f32x4*)(F1 + k0);
      const f32x4 y1 = *(const f32x4*)(F1 + k0 + 4);
      bf16x8 p, q;
#pragma unroll
      for (int j = 0; j < 4; ++j) {
        p[j] = (bf16)x0[j]; p[j + 4] = (bf16)x1[j];
        q[j] = (bf16)y0[j]; q[j + 4] = (bf16)y1[j];
      }
      *(bf16x8*)(sA + c0 * 8) = p;
      *(bf16x8*)(sA + c1 * 8) = q;
    } else {
      async_lds16(A0 + k0, sA + c0 * 8);
      async_lds16(A1 + k0, sA + c1 * 8);
    }
    async_lds16(B0 + k0, sB + c0 * 8);
    async_lds16(B1 + k0, sB + c1 * 8);
    __syncthreads();
    bf16x8 a[4], b[4];
#pragma unroll
    for (int i = 0; i < 4; ++i)
      a[i] = *(const bf16x8*)(sA + (wr + i * 16 + fm) * 32 + fq * 8);
#pragma unroll
    for (int j = 0; j < 4; ++j)
      b[j] = *(const bf16x8*)(sB + (wc + j * 16 + fm) * 32 + fq * 8);
#pragma unroll
    for (int i = 0; i < 4; ++i)
#pragma unroll
      for (int j = 0; j < 4; ++j)
        acc[i][j] = MFMA16(a[i], b[j], acc[i][j]);
  }

  // epilogue; C/D layout: col = lane&15, row = (lane>>4)*4 + r
#pragma unroll
  for (int i = 0; i < 4; ++i) {
#pragma unroll
    for (int r = 0; r < 4; ++r) {
      const long R = rowBase + wr + i * 16 + fq * 4 + r;
      const float mk = mask ? (float)mask[R] : 1.0f;
      const bf16* resrow = resid ? resid + R * 512 : nullptr;
      bf16* outrow = out + R * 512;
#pragma unroll
      for (int j = 0; j < 4; ++j) {
        const int C = colBase + wc + j * 16 + fm;
        float v = acc[i][j][r] + (float)bias[C];
        if (mask) v *= mk;
        if (resid) v = (float)resrow[C] + fmaxf(v, 0.0f);
        outrow[C] = (bf16)v;
      }
    }
  }
}

// ---------------------------------------------------------------------------
// Attention: block per (q-tile 64, batch, head). 4 waves; wave owns 16 q-rows.
// S^T layout: QK MFMA as (A=K rows, B=Q rows) -> lane holds q=fm, kk=quad*4+r
//   -> qm per-lane scalar, km b128 LDS read, sX written as b64 (4 bf16/kk).
// PV: A = sX rows (q), B = sVt rows (d) from pre-transposed global Vt.
// All stride-72 LDS tiles: b128 frag reads and staging writes conflict-free.
// Writes O in-place over Qp (own tile staged to sQ before any store).
// ---------------------------------------------------------------------------
__global__ __launch_bounds__(256) void attn_kernel(
    bf16* __restrict__ Qp, const bf16* __restrict__ Kp,
    const bf16* __restrict__ Vt, const bf16* __restrict__ Qm,
    const bf16* __restrict__ Km) {
  __shared__ bf16 sQ[64][72];      // [q][d]
  __shared__ bf16 sK[64][72];      // [kk][d]
  __shared__ bf16 sVt[64][72];     // [d][kk]
  __shared__ bf16 sX[4][16][72];   // per-wave [q][kk]
  __shared__ float sKm[64];
  __shared__ float sL[4][16];

  const int tid = threadIdx.x;
  const int lane = tid & 63;
  const int w = tid >> 6;
  const int fm = lane & 15;
  const int fq = lane >> 4;
  const int q0 = blockIdx.x * 64;
  const int b = blockIdx.y;
  const int hh = blockIdx.z;

  bf16* Qbase = Qp + ((long)b * 1024 + q0) * 512 + hh * 64;
  for (int c = tid; c < 512; c += 256) {
    const int row = c >> 3, col = (c & 7) * 8;
    *(bf16x8*)(&sQ[row][col]) = *(const bf16x8*)(Qbase + (long)row * 512 + col);
  }
  const float qm_lane = (float)Qm[(long)b * 1024 + q0 + w * 16 + fm];

  f32x4 acc_o[4] = {};
  float l_lane = 0.f;
  const float scale = 0.04419417382415922f;  // 1/sqrt(512)

  const bf16* Vthead = Vt + ((long)b * 8 + hh) * 64 * 1024;  // [d][kk]

  for (int kt = 0; kt < 16; ++kt) {
    const int kk0 = kt * 64;
    __syncthreads();
    const bf16* Kbase = Kp + ((long)b * 1024 + kk0) * 512 + hh * 64;
    for (int c = tid; c < 512; c += 256) {
      const int row = c >> 3, col = (c & 7) * 8;
      *(bf16x8*)(&sK[row][col]) = *(const bf16x8*)(Kbase + (long)row * 512 + col);
      *(bf16x8*)(&sVt[row][col]) =
          *(const bf16x8*)(Vthead + (long)row * 1024 + kk0 + col);
    }
    if (tid < 64) sKm[tid] = (float)Km[(long)b * 1024 + kk0 + tid];
    __syncthreads();

    // S^T: per wave C[kk 64][q 16]; A = K rows (m=kk), B = Q rows (n=q)
    bf16x8 qf[2];
    qf[0] = *(const bf16x8*)(&sQ[w * 16 + fm][fq * 8]);
    qf[1] = *(const bf16x8*)(&sQ[w * 16 + fm][32 + fq * 8]);
    f32x4 s_acc[4] = {};
#pragma unroll
    for (int ks = 0; ks < 2; ++ks)
#pragma unroll
      for (int t = 0; t < 4; ++t) {
        const bf16x8 kf = *(const bf16x8*)(&sK[t * 16 + fm][ks * 32 + fq * 8]);
        s_acc[t] = MFMA16(kf, qf[ks], s_acc[t]);
      }
    // lane holds q=fm, kk = t*16 + fq*4 + r
#pragma unroll
    for (int t = 0; t < 4; ++t) {
      const f32x4 km4 = *(const f32x4*)(&sKm[t * 16 + fq * 4]);
      bf16x4 xp;
#pragma unroll
      for (int r = 0; r < 4; ++r) {
        const float s = s_acc[t][r] * scale;
        const float x = __expf(__expf(s) * km4[r]) * qm_lane;
        l_lane += x;
        xp[r] = (bf16)x;
      }
      *(bf16x4*)((void*)&sX[w][fm][t * 16 + fq * 4]) = xp;  // b64, 8B-aligned
    }
    __syncthreads();  // sX visible (also covers cross-lane A-frag reads)
    // PV: C[q 16][d 64]; A = sX rows (m=q), B = sVt rows (n=d)
#pragma unroll
    for (int ks = 0; ks < 2; ++ks) {
      const bf16x8 xf = *(const bf16x8*)(&sX[w][fm][ks * 32 + fq * 8]);
#pragma unroll
      for (int t = 0; t < 4; ++t) {
        const bf16x8 vf = *(const bf16x8*)(&sVt[t * 16 + fm][ks * 32 + fq * 8]);
        acc_o[t] = MFMA16(xf, vf, acc_o[t]);
      }
    }
  }

  // row-sum: in-lane partial (q=fm) -> sum over fq groups
  l_lane += __shfl_xor(l_lane, 16);
  l_lane += __shfl_xor(l_lane, 32);
  if (fq == 0) sL[w][fm] = l_lane;
  __syncthreads();

  float linv[4];
#pragma unroll
  for (int r = 0; r < 4; ++r) linv[r] = 1.0f / (sL[w][fq * 4 + r] + 1e-8f);

#pragma unroll
  for (int t = 0; t < 4; ++t) {
#pragma unroll
    for (int r = 0; r < 4; ++r) {
      const int qr = w * 16 + fq * 4 + r;
      const int dc = t * 16 + fm;
      const float val = (float)sQ[qr][dc] + acc_o[t][r] * linv[r];
      Qbase[(long)qr * 512 + dc] = (bf16)val;
    }
  }
}

// ---------------------------------------------------------------------------
// LayerNorm (bf16 -> bf16). One wave per row. In-place safe.
// ---------------------------------------------------------------------------
__global__ __launch_bounds__(256) void lnorm(
    const bf16* __restrict__ X, const bf16* __restrict__ g,
    const bf16* __restrict__ bb, bf16* __restrict__ out) {
  const int row = blockIdx.x * 4 + (threadIdx.x >> 6);
  const int lane = threadIdx.x & 63;
  const bf16x8 v = *(const bf16x8*)(X + (size_t)row * 512 + lane * 8);
  float x[8], s = 0.f, ss = 0.f;
#pragma unroll
  for (int j = 0; j < 8; ++j) {
    x[j] = (float)v[j];
    s += x[j];
    ss += x[j] * x[j];
  }
#pragma unroll
  for (int m = 1; m < 64; m <<= 1) {
    s += __shfl_xor(s, m);
    ss += __shfl_xor(ss, m);
  }
  const float mean = s * (1.0f / 512.0f);
  const float var = ss * (1.0f / 512.0f) - mean * mean;
  const float rstd = 1.0f / sqrtf(var + 1e-5f);
  const bf16x8 gv = *(const bf16x8*)(g + lane * 8);
  const bf16x8 bv = *(const bf16x8*)(bb + lane * 8);
  bf16x8 o;
#pragma unroll
  for (int j = 0; j < 8; ++j)
    o[j] = (bf16)((x[j] - mean) * rstd * (float)gv[j] + (float)bv[j]);
  *(bf16x8*)(out + (size_t)row * 512 + lane * 8) = o;
}

// ---------------------------------------------------------------------------
// Final LayerNorm: bf16 in, f32 out.
// ---------------------------------------------------------------------------
__global__ __launch_bounds__(256) void lnorm_out(
    const bf16* __restrict__ X, const bf16* __restrict__ g,
    const bf16* __restrict__ bb, float* __restrict__ out) {
  const int row = blockIdx.x * 4 + (threadIdx.x >> 6);
  const int lane = threadIdx.x & 63;
  const bf16x8 v = *(const bf16x8*)(X + (size_t)row * 512 + lane * 8);
  float x[8], s = 0.f, ss = 0.f;
#pragma unroll
  for (int j = 0; j < 8; ++j) {
    x[j] = (float)v[j];
    s += x[j];
    ss += x[j] * x[j];
  }
#pragma unroll
  for (int m = 1; m < 64; m <<= 1) {
    s += __shfl_xor(s, m);
    ss += __shfl_xor(ss, m);
  }
  const float mean = s * (1.0f / 512.0f);
  const float var = ss * (1.0f / 512.0f) - mean * mean;
  const float rstd = 1.0f / sqrtf(var + 1e-5f);
  const bf16x8 gv = *(const bf16x8*)(g + lane * 8);
  const bf16x8 bv = *(const bf16x8*)(bb + lane * 8);
  f32x4 a, c;
#pragma unroll
  for (int j = 0; j < 4; ++j) {
    a[j] = (x[j] - mean) * rstd * (float)gv[j] + (float)bv[j];
    c[j] = (x[j + 4] - mean) * rstd * (float)gv[j + 4] + (float)bv[j + 4];
  }
  float* fo = out + (size_t)row * 512 + lane * 8;
  *(f32x4*)fo = a;
  *(f32x4*)(fo + 4) = c;
}

// ---------------------------------------------------------------------------
extern "C" void kernel_launch(void* const* d_in, const int* in_sizes, int n_in,
                              void* d_out, int out_size, void* d_ws, size_t ws_size,
                              hipStream_t stream) {
  (void)in_sizes; (void)n_in; (void)out_size; (void)ws_size;
  const float* Q = (const float*)d_in[0];
  const float* K = (const float*)d_in[1];

  bf16* ws = (bf16*)d_ws;
  const long W2 = 512L * 512;
  const long MN = 16384L * 512;
  bf16* Tq = ws;                           // 4 transposed bf16 weights: 2MB
  bf16* Tk = Tq + W2;
  bf16* Tv = Tk + W2;
  bf16* To = Tv + W2;
  bf16* sm = To + W2;                      // 8 x 512 smalls
  bf16* cQm = sm + 8 * 512;                // 16384
  bf16* cKm = cQm + 16384;                 // 16384
  bf16* Qp = cKm + 16384;                  // 16MB
  bf16* Kp = Qp + MN;                      // 16MB
  bf16* Vx = (bf16*)d_out;                 // V proj (bf16) in d_out lower 16MB
  bf16* Vt = (bf16*)d_out + MN;            // V^T (bf16) in d_out upper 16MB
                                           // (out f32 = 32MB; both dead pre-LN1)
  bf16* cbq = sm + 0 * 512;
  bf16* cbk = sm + 1 * 512;
  bf16* cbv = sm + 2 * 512;
  bf16* cbo = sm + 3 * 512;
  bf16* cg0 = sm + 4 * 512;
  bf16* cb0 = sm + 5 * 512;
  bf16* cg1 = sm + 6 * 512;
  bf16* cb1 = sm + 7 * 512;

  transposeW<<<dim3(8, 8, 4), 256, 0, stream>>>(
      (const float*)d_in[4], (const float*)d_in[6],
      (const float*)d_in[8], (const float*)d_in[10], Tq, Tk, Tv, To);

  ConvArgs ca;
  ca.src[0] = (const float*)d_in[2];  ca.dst[0] = cQm; ca.n[0] = 16384;
  ca.src[1] = (const float*)d_in[3];  ca.dst[1] = cKm; ca.n[1] = 16384;
  ca.src[2] = (const float*)d_in[5];  ca.dst[2] = cbq; ca.n[2] = 512;
  ca.src[3] = (const float*)d_in[7];  ca.dst[3] = cbk; ca.n[3] = 512;
  ca.src[4] = (const float*)d_in[9];  ca.dst[4] = cbv; ca.n[4] = 512;
  ca.src[5] = (const float*)d_in[11]; ca.dst[5] = cbo; ca.n[5] = 512;
  ca.src[6] = (const float*)d_in[12]; ca.dst[6] = cg0; ca.n[6] = 512;
  ca.src[7] = (const float*)d_in[13]; ca.dst[7] = cb0; ca.n[7] = 512;
  ca.src[8] = (const float*)d_in[14]; ca.dst[8] = cg1; ca.n[8] = 512;
  ca.src[9] = (const float*)d_in[15]; ca.dst[9] = cb1; ca.n[9] = 512;
  convert_all<<<dim3(8, 1, 10), 256, 0, stream>>>(ca);

  const dim3 gg(4, 128);
  gemm512<true><<<gg, 256, 0, stream>>>(Q, Tq, cbq, cQm, nullptr, Qp);
  gemm512<true><<<gg, 256, 0, stream>>>(K, Tk, cbk, cKm, nullptr, Kp);
  gemm512<true><<<gg, 256, 0, stream>>>(K, Tv, cbv, nullptr, nullptr, Vx);

  transposeV<<<dim3(16, 8, 16), 256, 0, stream>>>(Vx, Vt);

  attn_kernel<<<dim3(16, 16, 8), 256, 0, stream>>>(Qp, Kp, Vt, cQm, cKm);

  lnorm<<<4096, 256, 0, stream>>>(Qp, cg0, cb0, Qp);
  gemm512<false><<<gg, 256, 0, stream>>>(Qp, To, cbo, nullptr, Qp, Kp);
  lnorm_out<<<4096, 256, 0, stream>>>(Kp, cg1, cb1, (float*)d_out);
}

// Round 5
// 343.591 us; speedup vs baseline: 1.0834x; 1.0225x over previous
//
#include <hip/hip_runtime.h>
#include <hip/hip_bf16.h>
#include <cstdint>

// ---------------------------------------------------------------------------
// MAB block (f32 in/out, bf16 internal):
//   Qp=(Q@Wq+bq)*Qm; Kp=(K@Wk+bk)*Km; V=K@Wv+bv
//   S = Qh Kh^T / sqrt(512);  X = exp(exp(S)*Km)*Qm;  A = X/(sum+1e-8)
//   O = Qh + A@Vh;  O = LN0(O);  O = O + relu(O@Wo+bo);  out = LN1(O)
//
// R5: (1) f32-A gemms: register prefetch of next K-tile overlaps HBM latency
//     with MFMA phase (was: synchronous loads stalling between barriers).
//     (2) attn elementwise: exp2-folded constants, km*log2e staged, binary Qm
//     factored out of the inner loop (exact for qm in {0,1}).
//     (3) removed per-iter sX barrier (sX strictly per-wave; lgkmcnt orders).
// ws ~ 36MB: T(2MB) + smalls + masks + Qp(16MB) + Kp(16MB).
// d_out (32MB f32) doubles as V(bf16) + Vt(bf16) scratch, dead before LN1.
// ---------------------------------------------------------------------------

typedef __bf16 bf16;
typedef __bf16 bf16x4 __attribute__((ext_vector_type(4)));
typedef __bf16 bf16x8 __attribute__((ext_vector_type(8)));
typedef float f32x4 __attribute__((ext_vector_type(4)));

#define MFMA16(a, b, c) __builtin_amdgcn_mfma_f32_16x16x32_bf16((a), (b), (c), 0, 0, 0)

#if __has_builtin(__builtin_amdgcn_exp2f)
#define EXP2F(x) __builtin_amdgcn_exp2f(x)
#else
#define EXP2F(x) exp2f(x)
#endif

static __device__ __forceinline__ void async_lds16(const bf16* g, bf16* l) {
  __builtin_amdgcn_global_load_lds(
      (__attribute__((address_space(1))) void*)(void*)g,
      (__attribute__((address_space(3))) void*)l,
      16, 0, 0);
}

// ---------------------------------------------------------------------------
// Weight convert+transpose: T[n][k] = (bf16)W[k][n], 512x512, f32 in.
// ---------------------------------------------------------------------------
__global__ __launch_bounds__(256) void transposeW(
    const float* __restrict__ Wq, const float* __restrict__ Wk,
    const float* __restrict__ Wv, const float* __restrict__ Wo,
    bf16* __restrict__ Tq, bf16* __restrict__ Tk,
    bf16* __restrict__ Tv, bf16* __restrict__ To) {
  const float* src;
  bf16* dst;
  switch (blockIdx.z) {
    case 0: src = Wq; dst = Tq; break;
    case 1: src = Wk; dst = Tk; break;
    case 2: src = Wv; dst = Tv; break;
    default: src = Wo; dst = To; break;
  }
  __shared__ bf16 t[64][72];
  const int tid = threadIdx.x;
  const int n0 = blockIdx.x * 64;
  const int k0 = blockIdx.y * 64;
  for (int c = tid; c < 512; c += 256) {
    const int row = c >> 3, col = (c & 7) * 8;   // row: k, col: n
    const float* sp = src + (size_t)(k0 + row) * 512 + n0 + col;
    const f32x4 a = *(const f32x4*)sp;
    const f32x4 b = *(const f32x4*)(sp + 4);
    bf16x8 v;
#pragma unroll
    for (int j = 0; j < 4; ++j) { v[j] = (bf16)a[j]; v[j + 4] = (bf16)b[j]; }
    *(bf16x8*)(&t[row][col]) = v;
  }
  __syncthreads();
  for (int c = tid; c < 512; c += 256) {
    const int row = c >> 3, col8 = (c & 7) * 8;  // row: n, col8: k
    bf16x8 v;
#pragma unroll
    for (int j = 0; j < 8; ++j) v[j] = t[col8 + j][row];
    *(bf16x8*)(dst + (size_t)(n0 + row) * 512 + k0 + col8) = v;
  }
}

// ---------------------------------------------------------------------------
// Batched f32->bf16 conversion of 10 small arrays.
// ---------------------------------------------------------------------------
struct ConvArgs {
  const float* src[10];
  bf16* dst[10];
  int n[10];
};

__global__ __launch_bounds__(256) void convert_all(ConvArgs a) {
  const int seg = blockIdx.z;
  const int n = a.n[seg];
  const long i = ((long)blockIdx.x * 256 + threadIdx.x) * 8;
  if (i >= n) return;
  const float* s = a.src[seg];
  const f32x4 x0 = *(const f32x4*)(s + i);
  const f32x4 x1 = *(const f32x4*)(s + i + 4);
  bf16x8 o;
#pragma unroll
  for (int j = 0; j < 4; ++j) { o[j] = (bf16)x0[j]; o[j + 4] = (bf16)x1[j]; }
  *(bf16x8*)(a.dst[seg] + i) = o;
}

// ---------------------------------------------------------------------------
// V transpose: Vt[(b*8+h)*64 + d][kk] = V[b][kk][h*64+d]. 64x64 tiles.
// ---------------------------------------------------------------------------
__global__ __launch_bounds__(256) void transposeV(
    const bf16* __restrict__ V, bf16* __restrict__ Vt) {
  __shared__ bf16 t[64][72];
  const int tid = threadIdx.x;
  const int kk0 = blockIdx.x * 64;
  const int d0 = blockIdx.y * 64;
  const int b = blockIdx.z;
  const bf16* src = V + ((long)b * 1024 + kk0) * 512 + d0;
  for (int c = tid; c < 512; c += 256) {
    const int row = c >> 3, col = (c & 7) * 8;   // row: kk, col: d
    *(bf16x8*)(&t[row][col]) = *(const bf16x8*)(src + (long)row * 512 + col);
  }
  __syncthreads();
  bf16* dst = Vt + ((long)b * 8 + (d0 >> 6)) * 64 * 1024 + kk0;
  for (int c = tid; c < 512; c += 256) {
    const int drow = c >> 3, col8 = (c & 7) * 8; // drow: d, col8: kk
    bf16x8 v;
#pragma unroll
    for (int j = 0; j < 8; ++j) v[j] = t[col8 + j][drow];
    *(bf16x8*)(dst + (long)drow * 1024 + col8) = v;
  }
}

// ---------------------------------------------------------------------------
// GEMM: out[M x 512] = epilogue(A[M x 512] @ Bt^T + bias). A f32 or bf16.
//   mask != null : out = (acc+bias) * mask[row]
//   resid != null: out = resid + relu(acc+bias)
// f32 path: register double-buffer of the A tile (prefetch overlaps MFMA).
// ---------------------------------------------------------------------------
template <bool AF32>
__global__ __launch_bounds__(256) void gemm512(
    const void* __restrict__ A, const bf16* __restrict__ Bt,
    const bf16* __restrict__ bias, const bf16* __restrict__ mask,
    const bf16* __restrict__ resid, bf16* __restrict__ out) {
  __shared__ bf16 sA[128 * 32];
  __shared__ bf16 sB[128 * 32];
  const int tid = threadIdx.x;
  const int lane = tid & 63;
  const int w = tid >> 6;
  const int fm = lane & 15;
  const int fq = lane >> 4;
  const long rowBase = (long)blockIdx.y * 128;
  const int colBase = blockIdx.x * 128;

  f32x4 acc[4][4] = {};

  const int c0 = tid, c1 = tid + 256;
  const int r0 = c0 >> 2, o0 = (c0 & 3) * 8;
  const int r1 = c1 >> 2, o1 = (c1 & 3) * 8;
  const bf16* A0 = (const bf16*)A + (rowBase + r0) * 512 + o0;
  const bf16* A1 = (const bf16*)A + (rowBase + r1) * 512 + o1;
  const float* F0 = (const float*)A + (rowBase + r0) * 512 + o0;
  const float* F1 = (const float*)A + (rowBase + r1) * 512 + o1;
  const bf16* B0 = Bt + (size_t)(colBase + r0) * 512 + o0;
  const bf16* B1 = Bt + (size_t)(colBase + r1) * 512 + o1;

  const int wr = (w & 1) * 64;
  const int wc = (w >> 1) * 64;

  f32x4 nx0, nx1, ny0, ny1;
  if (AF32) {
    nx0 = *(const f32x4*)(F0);
    nx1 = *(const f32x4*)(F0 + 4);
    ny0 = *(const f32x4*)(F1);
    ny1 = *(const f32x4*)(F1 + 4);
  }

  for (int kt = 0; kt < 16; ++kt) {
    const int k0 = kt * 32;
    __syncthreads();
    if (AF32) {
      bf16x8 p, q;
#pragma unroll
      for (int j = 0; j < 4; ++j) {
        p[j] = (bf16)nx0[j]; p[j + 4] = (bf16)nx1[j];
        q[j] = (bf16)ny0[j]; q[j + 4] = (bf16)ny1[j];
      }
      *(bf16x8*)(sA + c0 * 8) = p;
      *(bf16x8*)(sA + c1 * 8) = q;
      if (kt < 15) {  // prefetch next tile; completes during MFMA phase
        nx0 = *(const f32x4*)(F0 + k0 + 32);
        nx1 = *(const f32x4*)(F0 + k0 + 36);
        ny0 = *(const f32x4*)(F1 + k0 + 32);
        ny1 = *(const f32x4*)(F1 + k0 + 36);
      }
    } else {
      async_lds16(A0 + k0, sA + c0 * 8);
      async_lds16(A1 + k0, sA + c1 * 8);
    }
    async_lds16(B0 + k0, sB + c0 * 8);
    async_lds16(B1 + k0, sB + c1 * 8);
    __syncthreads();
    bf16x8 a[4], b[4];
#pragma unroll
    for (int i = 0; i < 4; ++i)
      a[i] = *(const bf16x8*)(sA + (wr + i * 16 + fm) * 32 + fq * 8);
#pragma unroll
    for (int j = 0; j < 4; ++j)
      b[j] = *(const bf16x8*)(sB + (wc + j * 16 + fm) * 32 + fq * 8);
#pragma unroll
    for (int i = 0; i < 4; ++i)
#pragma unroll
      for (int j = 0; j < 4; ++j)
        acc[i][j] = MFMA16(a[i], b[j], acc[i][j]);
  }

  // epilogue; C/D layout: col = lane&15, row = (lane>>4)*4 + r
#pragma unroll
  for (int i = 0; i < 4; ++i) {
#pragma unroll
    for (int r = 0; r < 4; ++r) {
      const long R = rowBase + wr + i * 16 + fq * 4 + r;
      const float mk = mask ? (float)mask[R] : 1.0f;
      const bf16* resrow = resid ? resid + R * 512 : nullptr;
      bf16* outrow = out + R * 512;
#pragma unroll
      for (int j = 0; j < 4; ++j) {
        const int C = colBase + wc + j * 16 + fm;
        float v = acc[i][j][r] + (float)bias[C];
        if (mask) v *= mk;
        if (resid) v = (float)resrow[C] + fmaxf(v, 0.0f);
        outrow[C] = (bf16)v;
      }
    }
  }
}

// ---------------------------------------------------------------------------
// Attention: block per (q-tile 64, batch, head). 4 waves; wave owns 16 q-rows.
// S^T MFMA (A=K rows, B=Q rows) -> lane holds q=fm, kk=fq*4+r (4-consec).
// Elementwise: y = exp2(exp2(s*c1) * kml), kml = km*log2e staged in LDS;
// binary Qm factored out (applied once in epilogue: exact for qm in {0,1}).
// PV: A = sX rows (q), B = sVt rows (d) from pre-transposed Vt.
// 2 barriers/iter; sX is per-wave (no barrier between write and PV read).
// ---------------------------------------------------------------------------
__global__ __launch_bounds__(256) void attn_kernel(
    bf16* __restrict__ Qp, const bf16* __restrict__ Kp,
    const bf16* __restrict__ Vt, const bf16* __restrict__ Qm,
    const bf16* __restrict__ Km) {
  __shared__ bf16 sQ[64][72];      // [q][d]
  __shared__ bf16 sK[64][72];      // [kk][d]
  __shared__ bf16 sVt[64][72];     // [d][kk]
  __shared__ bf16 sX[4][16][72];   // per-wave [q][kk]
  __shared__ float sKl[64];        // km * log2e
  __shared__ float sL[4][16];

  const int tid = threadIdx.x;
  const int lane = tid & 63;
  const int w = tid >> 6;
  const int fm = lane & 15;
  const int fq = lane >> 4;
  const int q0 = blockIdx.x * 64;
  const int b = blockIdx.y;
  const int hh = blockIdx.z;

  bf16* Qbase = Qp + ((long)b * 1024 + q0) * 512 + hh * 64;
  for (int c = tid; c < 512; c += 256) {
    const int row = c >> 3, col = (c & 7) * 8;
    *(bf16x8*)(&sQ[row][col]) = *(const bf16x8*)(Qbase + (long)row * 512 + col);
  }
  const float qm_lane = (float)Qm[(long)b * 1024 + q0 + w * 16 + fm];

  f32x4 acc_o[4] = {};
  float l_lane = 0.f;
  // c1 = (1/sqrt(512)) * log2(e)
  const float c1 = 0.063758715f;
  const float LOG2E = 1.4426950408889634f;

  const bf16* Vthead = Vt + ((long)b * 8 + hh) * 64 * 1024;  // [d][kk]
  const bf16* Kbb = Kp + (long)b * 1024 * 512 + hh * 64;
  const bf16* Kmb = Km + (long)b * 1024;

  for (int kt = 0; kt < 16; ++kt) {
    const int kk0 = kt * 64;
    __syncthreads();
    const bf16* Kbase = Kbb + (long)kk0 * 512;
    for (int c = tid; c < 512; c += 256) {
      const int row = c >> 3, col = (c & 7) * 8;
      *(bf16x8*)(&sK[row][col]) = *(const bf16x8*)(Kbase + (long)row * 512 + col);
      *(bf16x8*)(&sVt[row][col]) =
          *(const bf16x8*)(Vthead + (long)row * 1024 + kk0 + col);
    }
    if (tid < 64) sKl[tid] = (float)Kmb[kk0 + tid] * LOG2E;
    __syncthreads();

    // S^T: per wave C[kk 64][q 16]; A = K rows (m=kk), B = Q rows (n=q)
    bf16x8 qf[2];
    qf[0] = *(const bf16x8*)(&sQ[w * 16 + fm][fq * 8]);
    qf[1] = *(const bf16x8*)(&sQ[w * 16 + fm][32 + fq * 8]);
    f32x4 s_acc[4] = {};
#pragma unroll
    for (int ks = 0; ks < 2; ++ks)
#pragma unroll
      for (int t = 0; t < 4; ++t) {
        const bf16x8 kf = *(const bf16x8*)(&sK[t * 16 + fm][ks * 32 + fq * 8]);
        s_acc[t] = MFMA16(kf, qf[ks], s_acc[t]);
      }
    // lane holds q=fm, kk = t*16 + fq*4 + r;  y = exp2(exp2(s*c1)*kml)
#pragma unroll
    for (int t = 0; t < 4; ++t) {
      const f32x4 kml4 = *(const f32x4*)(&sKl[t * 16 + fq * 4]);
      bf16x4 xp;
#pragma unroll
      for (int r = 0; r < 4; ++r) {
        const float e1 = EXP2F(s_acc[t][r] * c1);
        const float y = EXP2F(e1 * kml4[r]);
        l_lane += y;
        xp[r] = (bf16)y;
      }
      *(bf16x4*)((void*)&sX[w][fm][t * 16 + fq * 4]) = xp;  // b64, own wave
    }
    // PV: C[q 16][d 64]; A = sX rows (m=q), B = sVt rows (n=d)
#pragma unroll
    for (int ks = 0; ks < 2; ++ks) {
      const bf16x8 xf = *(const bf16x8*)(&sX[w][fm][ks * 32 + fq * 8]);
#pragma unroll
      for (int t = 0; t < 4; ++t) {
        const bf16x8 vf = *(const bf16x8*)(&sVt[t * 16 + fm][ks * 32 + fq * 8]);
        acc_o[t] = MFMA16(xf, vf, acc_o[t]);
      }
    }
  }

  // per-q Y-sums: lane partial (q=fm) -> total across fq groups
  l_lane += __shfl_xor(l_lane, 16);
  l_lane += __shfl_xor(l_lane, 32);
  if (fq == 0) sL[w][fm] = l_lane;

  // epilogue: lane holds q = fq*4+r, d = fm (PV C-layout)
#pragma unroll
  for (int t = 0; t < 4; ++t) {
#pragma unroll
    for (int r = 0; r < 4; ++r) {
      const int qr = w * 16 + fq * 4 + r;
      const int dc = t * 16 + fm;
      const float qm_r = __shfl(qm_lane, fq * 4 + r, 64);
      const float li = 1.0f / (qm_r * sL[w][fq * 4 + r] + 1e-8f);
      const float val = (float)sQ[qr][dc] + qm_r * acc_o[t][r] * li;
      Qbase[(long)qr * 512 + dc] = (bf16)val;
    }
  }
}

// ---------------------------------------------------------------------------
// LayerNorm (bf16 -> bf16). One wave per row. In-place safe.
// ---------------------------------------------------------------------------
__global__ __launch_bounds__(256) void lnorm(
    const bf16* __restrict__ X, const bf16* __restrict__ g,
    const bf16* __restrict__ bb, bf16* __restrict__ out) {
  const int row = blockIdx.x * 4 + (threadIdx.x >> 6);
  const int lane = threadIdx.x & 63;
  const bf16x8 v = *(const bf16x8*)(X + (size_t)row * 512 + lane * 8);
  float x[8], s = 0.f, ss = 0.f;
#pragma unroll
  for (int j = 0; j < 8; ++j) {
    x[j] = (float)v[j];
    s += x[j];
    ss += x[j] * x[j];
  }
#pragma unroll
  for (int m = 1; m < 64; m <<= 1) {
    s += __shfl_xor(s, m);
    ss += __shfl_xor(ss, m);
  }
  const float mean = s * (1.0f / 512.0f);
  const float var = ss * (1.0f / 512.0f) - mean * mean;
  const float rstd = 1.0f / sqrtf(var + 1e-5f);
  const bf16x8 gv = *(const bf16x8*)(g + lane * 8);
  const bf16x8 bv = *(const bf16x8*)(bb + lane * 8);
  bf16x8 o;
#pragma unroll
  for (int j = 0; j < 8; ++j)
    o[j] = (bf16)((x[j] - mean) * rstd * (float)gv[j] + (float)bv[j]);
  *(bf16x8*)(out + (size_t)row * 512 + lane * 8) = o;
}

// ---------------------------------------------------------------------------
// Final LayerNorm: bf16 in, f32 out.
// ---------------------------------------------------------------------------
__global__ __launch_bounds__(256) void lnorm_out(
    const bf16* __restrict__ X, const bf16* __restrict__ g,
    const bf16* __restrict__ bb, float* __restrict__ out) {
  const int row = blockIdx.x * 4 + (threadIdx.x >> 6);
  const int lane = threadIdx.x & 63;
  const bf16x8 v = *(const bf16x8*)(X + (size_t)row * 512 + lane * 8);
  float x[8], s = 0.f, ss = 0.f;
#pragma unroll
  for (int j = 0; j < 8; ++j) {
    x[j] = (float)v[j];
    s += x[j];
    ss += x[j] * x[j];
  }
#pragma unroll
  for (int m = 1; m < 64; m <<= 1) {
    s += __shfl_xor(s, m);
    ss += __shfl_xor(ss, m);
  }
  const float mean = s * (1.0f / 512.0f);
  const float var = ss * (1.0f / 512.0f) - mean * mean;
  const float rstd = 1.0f / sqrtf(var + 1e-5f);
  const bf16x8 gv = *(const bf16x8*)(g + lane * 8);
  const bf16x8 bv = *(const bf16x8*)(bb + lane * 8);
  f32x4 a, c;
#pragma unroll
  for (int j = 0; j < 4; ++j) {
    a[j] = (x[j] - mean) * rstd * (float)gv[j] + (float)bv[j];
    c[j] = (x[j + 4] - mean) * rstd * (float)gv[j + 4] + (float)bv[j + 4];
  }
  float* fo = out + (size_t)row * 512 + lane * 8;
  *(f32x4*)fo = a;
  *(f32x4*)(fo + 4) = c;
}

// ---------------------------------------------------------------------------
extern "C" void kernel_launch(void* const* d_in, const int* in_sizes, int n_in,
                              void* d_out, int out_size, void* d_ws, size_t ws_size,
                              hipStream_t stream) {
  (void)in_sizes; (void)n_in; (void)out_size; (void)ws_size;
  const float* Q = (const float*)d_in[0];
  const float* K = (const float*)d_in[1];

  bf16* ws = (bf16*)d_ws;
  const long W2 = 512L * 512;
  const long MN = 16384L * 512;
  bf16* Tq = ws;                           // 4 transposed bf16 weights: 2MB
  bf16* Tk = Tq + W2;
  bf16* Tv = Tk + W2;
  bf16* To = Tv + W2;
  bf16* sm = To + W2;                      // 8 x 512 smalls
  bf16* cQm = sm + 8 * 512;                // 16384
  bf16* cKm = cQm + 16384;                 // 16384
  bf16* Qp = cKm + 16384;                  // 16MB
  bf16* Kp = Qp + MN;                      // 16MB
  bf16* Vx = (bf16*)d_out;                 // V proj (bf16) in d_out lower 16MB
  bf16* Vt = (bf16*)d_out + MN;            // V^T (bf16) in d_out upper 16MB

  bf16* cbq = sm + 0 * 512;
  bf16* cbk = sm + 1 * 512;
  bf16* cbv = sm + 2 * 512;
  bf16* cbo = sm + 3 * 512;
  bf16* cg0 = sm + 4 * 512;
  bf16* cb0 = sm + 5 * 512;
  bf16* cg1 = sm + 6 * 512;
  bf16* cb1 = sm + 7 * 512;

  transposeW<<<dim3(8, 8, 4), 256, 0, stream>>>(
      (const float*)d_in[4], (const float*)d_in[6],
      (const float*)d_in[8], (const float*)d_in[10], Tq, Tk, Tv, To);

  ConvArgs ca;
  ca.src[0] = (const float*)d_in[2];  ca.dst[0] = cQm; ca.n[0] = 16384;
  ca.src[1] = (const float*)d_in[3];  ca.dst[1] = cKm; ca.n[1] = 16384;
  ca.src[2] = (const float*)d_in[5];  ca.dst[2] = cbq; ca.n[2] = 512;
  ca.src[3] = (const float*)d_in[7];  ca.dst[3] = cbk; ca.n[3] = 512;
  ca.src[4] = (const float*)d_in[9];  ca.dst[4] = cbv; ca.n[4] = 512;
  ca.src[5] = (const float*)d_in[11]; ca.dst[5] = cbo; ca.n[5] = 512;
  ca.src[6] = (const float*)d_in[12]; ca.dst[6] = cg0; ca.n[6] = 512;
  ca.src[7] = (const float*)d_in[13]; ca.dst[7] = cb0; ca.n[7] = 512;
  ca.src[8] = (const float*)d_in[14]; ca.dst[8] = cg1; ca.n[8] = 512;
  ca.src[9] = (const float*)d_in[15]; ca.dst[9] = cb1; ca.n[9] = 512;
  convert_all<<<dim3(8, 1, 10), 256, 0, stream>>>(ca);

  const dim3 gg(4, 128);
  gemm512<true><<<gg, 256, 0, stream>>>(Q, Tq, cbq, cQm, nullptr, Qp);
  gemm512<true><<<gg, 256, 0, stream>>>(K, Tk, cbk, cKm, nullptr, Kp);
  gemm512<true><<<gg, 256, 0, stream>>>(K, Tv, cbv, nullptr, nullptr, Vx);

  transposeV<<<dim3(16, 8, 16), 256, 0, stream>>>(Vx, Vt);

  attn_kernel<<<dim3(16, 16, 8), 256, 0, stream>>>(Qp, Kp, Vt, cQm, cKm);

  lnorm<<<4096, 256, 0, stream>>>(Qp, cg0, cb0, Qp);
  gemm512<false><<<gg, 256, 0, stream>>>(Qp, To, cbo, nullptr, Qp, Kp);
  lnorm_out<<<4096, 256, 0, stream>>>(Kp, cg1, cb1, (float*)d_out);
}

// Round 6
// 311.437 us; speedup vs baseline: 1.1952x; 1.1032x over previous
//
#include <hip/hip_runtime.h>
#include <hip/hip_bf16.h>
#include <cstdint>

// ---------------------------------------------------------------------------
// MAB block (f32 in/out, bf16 internal):
//   Qp=(Q@Wq+bq)*Qm; Kp=(K@Wk+bk)*Km; V=K@Wv+bv
//   S = Qh Kh^T / sqrt(512);  X = exp(exp(S)*Km)*Qm;  A = X/(sum+1e-8)
//   O = Qh + A@Vh;  O = LN0(O);  O = O + relu(O@Wo+bo);  out = LN1(O)
//
// R6: (1) gemmKV fuses K-proj + V-proj + V-transpose: one f32 A staging
//     feeds two MFMA chains; V epilogue writes transposed directly (4
//     consecutive kk per acc reg -> 8B stores). Kills one f32 GEMM + the
//     transposeV pass. (2) attn: XCD swizzle (all q-tiles of one (b,h)
//     share id%8 -> same XCD L2 for K/V slices) + hoisted loop-invariant
//     Q fragments. (3) carried from R5: exp2-folded elementwise, factored
//     binary Qm, per-wave sX without barrier, f32 register prefetch.
// ws ~ 36MB. d_out (32MB f32) holds Vt (bf16, 16MB), dead before LN1.
// ---------------------------------------------------------------------------

typedef __bf16 bf16;
typedef __bf16 bf16x4 __attribute__((ext_vector_type(4)));
typedef __bf16 bf16x8 __attribute__((ext_vector_type(8)));
typedef float f32x4 __attribute__((ext_vector_type(4)));

#define MFMA16(a, b, c) __builtin_amdgcn_mfma_f32_16x16x32_bf16((a), (b), (c), 0, 0, 0)

#if __has_builtin(__builtin_amdgcn_exp2f)
#define EXP2F(x) __builtin_amdgcn_exp2f(x)
#else
#define EXP2F(x) exp2f(x)
#endif

static __device__ __forceinline__ void async_lds16(const bf16* g, bf16* l) {
  __builtin_amdgcn_global_load_lds(
      (__attribute__((address_space(1))) void*)(void*)g,
      (__attribute__((address_space(3))) void*)l,
      16, 0, 0);
}

// ---------------------------------------------------------------------------
// Weight convert+transpose: T[n][k] = (bf16)W[k][n], 512x512, f32 in.
// ---------------------------------------------------------------------------
__global__ __launch_bounds__(256) void transposeW(
    const float* __restrict__ Wq, const float* __restrict__ Wk,
    const float* __restrict__ Wv, const float* __restrict__ Wo,
    bf16* __restrict__ Tq, bf16* __restrict__ Tk,
    bf16* __restrict__ Tv, bf16* __restrict__ To) {
  const float* src;
  bf16* dst;
  switch (blockIdx.z) {
    case 0: src = Wq; dst = Tq; break;
    case 1: src = Wk; dst = Tk; break;
    case 2: src = Wv; dst = Tv; break;
    default: src = Wo; dst = To; break;
  }
  __shared__ bf16 t[64][72];
  const int tid = threadIdx.x;
  const int n0 = blockIdx.x * 64;
  const int k0 = blockIdx.y * 64;
  for (int c = tid; c < 512; c += 256) {
    const int row = c >> 3, col = (c & 7) * 8;   // row: k, col: n
    const float* sp = src + (size_t)(k0 + row) * 512 + n0 + col;
    const f32x4 a = *(const f32x4*)sp;
    const f32x4 b = *(const f32x4*)(sp + 4);
    bf16x8 v;
#pragma unroll
    for (int j = 0; j < 4; ++j) { v[j] = (bf16)a[j]; v[j + 4] = (bf16)b[j]; }
    *(bf16x8*)(&t[row][col]) = v;
  }
  __syncthreads();
  for (int c = tid; c < 512; c += 256) {
    const int row = c >> 3, col8 = (c & 7) * 8;  // row: n, col8: k
    bf16x8 v;
#pragma unroll
    for (int j = 0; j < 8; ++j) v[j] = t[col8 + j][row];
    *(bf16x8*)(dst + (size_t)(n0 + row) * 512 + k0 + col8) = v;
  }
}

// ---------------------------------------------------------------------------
// Batched f32->bf16 conversion of 10 small arrays.
// ---------------------------------------------------------------------------
struct ConvArgs {
  const float* src[10];
  bf16* dst[10];
  int n[10];
};

__global__ __launch_bounds__(256) void convert_all(ConvArgs a) {
  const int seg = blockIdx.z;
  const int n = a.n[seg];
  const long i = ((long)blockIdx.x * 256 + threadIdx.x) * 8;
  if (i >= n) return;
  const float* s = a.src[seg];
  const f32x4 x0 = *(const f32x4*)(s + i);
  const f32x4 x1 = *(const f32x4*)(s + i + 4);
  bf16x8 o;
#pragma unroll
  for (int j = 0; j < 4; ++j) { o[j] = (bf16)x0[j]; o[j + 4] = (bf16)x1[j]; }
  *(bf16x8*)(a.dst[seg] + i) = o;
}

// ---------------------------------------------------------------------------
// GEMM: out[M x 512] = epilogue(A[M x 512] @ Bt^T + bias). A f32 or bf16.
//   mask != null : out = (acc+bias) * mask[row]
//   resid != null: out = resid + relu(acc+bias)
// f32 path: register prefetch of next A tile overlaps HBM latency w/ MFMA.
// ---------------------------------------------------------------------------
template <bool AF32>
__global__ __launch_bounds__(256, 2) void gemm512(
    const void* __restrict__ A, const bf16* __restrict__ Bt,
    const bf16* __restrict__ bias, const bf16* __restrict__ mask,
    const bf16* __restrict__ resid, bf16* __restrict__ out) {
  __shared__ bf16 sA[128 * 32];
  __shared__ bf16 sB[128 * 32];
  const int tid = threadIdx.x;
  const int lane = tid & 63;
  const int w = tid >> 6;
  const int fm = lane & 15;
  const int fq = lane >> 4;
  const long rowBase = (long)blockIdx.y * 128;
  const int colBase = blockIdx.x * 128;

  f32x4 acc[4][4] = {};

  const int c0 = tid, c1 = tid + 256;
  const int r0 = c0 >> 2, o0 = (c0 & 3) * 8;
  const int r1 = c1 >> 2, o1 = (c1 & 3) * 8;
  const bf16* A0 = (const bf16*)A + (rowBase + r0) * 512 + o0;
  const bf16* A1 = (const bf16*)A + (rowBase + r1) * 512 + o1;
  const float* F0 = (const float*)A + (rowBase + r0) * 512 + o0;
  const float* F1 = (const float*)A + (rowBase + r1) * 512 + o1;
  const bf16* B0 = Bt + (size_t)(colBase + r0) * 512 + o0;
  const bf16* B1 = Bt + (size_t)(colBase + r1) * 512 + o1;

  const int wr = (w & 1) * 64;
  const int wc = (w >> 1) * 64;

  f32x4 nx0, nx1, ny0, ny1;
  if (AF32) {
    nx0 = *(const f32x4*)(F0);
    nx1 = *(const f32x4*)(F0 + 4);
    ny0 = *(const f32x4*)(F1);
    ny1 = *(const f32x4*)(F1 + 4);
  }

  for (int kt = 0; kt < 16; ++kt) {
    const int k0 = kt * 32;
    __syncthreads();
    if (AF32) {
      bf16x8 p, q;
#pragma unroll
      for (int j = 0; j < 4; ++j) {
        p[j] = (bf16)nx0[j]; p[j + 4] = (bf16)nx1[j];
        q[j] = (bf16)ny0[j]; q[j + 4] = (bf16)ny1[j];
      }
      *(bf16x8*)(sA + c0 * 8) = p;
      *(bf16x8*)(sA + c1 * 8) = q;
      if (kt < 15) {
        nx0 = *(const f32x4*)(F0 + k0 + 32);
        nx1 = *(const f32x4*)(F0 + k0 + 36);
        ny0 = *(const f32x4*)(F1 + k0 + 32);
        ny1 = *(const f32x4*)(F1 + k0 + 36);
      }
    } else {
      async_lds16(A0 + k0, sA + c0 * 8);
      async_lds16(A1 + k0, sA + c1 * 8);
    }
    async_lds16(B0 + k0, sB + c0 * 8);
    async_lds16(B1 + k0, sB + c1 * 8);
    __syncthreads();
    bf16x8 a[4], b[4];
#pragma unroll
    for (int i = 0; i < 4; ++i)
      a[i] = *(const bf16x8*)(sA + (wr + i * 16 + fm) * 32 + fq * 8);
#pragma unroll
    for (int j = 0; j < 4; ++j)
      b[j] = *(const bf16x8*)(sB + (wc + j * 16 + fm) * 32 + fq * 8);
#pragma unroll
    for (int i = 0; i < 4; ++i)
#pragma unroll
      for (int j = 0; j < 4; ++j)
        acc[i][j] = MFMA16(a[i], b[j], acc[i][j]);
  }

  // epilogue; C/D layout: col = lane&15, row = (lane>>4)*4 + r
#pragma unroll
  for (int i = 0; i < 4; ++i) {
#pragma unroll
    for (int r = 0; r < 4; ++r) {
      const long R = rowBase + wr + i * 16 + fq * 4 + r;
      const float mk = mask ? (float)mask[R] : 1.0f;
      const bf16* resrow = resid ? resid + R * 512 : nullptr;
      bf16* outrow = out + R * 512;
#pragma unroll
      for (int j = 0; j < 4; ++j) {
        const int C = colBase + wc + j * 16 + fm;
        float v = acc[i][j][r] + (float)bias[C];
        if (mask) v *= mk;
        if (resid) v = (float)resrow[C] + fmaxf(v, 0.0f);
        outrow[C] = (bf16)v;
      }
    }
  }
}

// ---------------------------------------------------------------------------
// Fused K/V projection: one f32 A staging feeds two MFMA chains.
//   Kp[R][C] = (A@Tk^T + bk)[R][C] * Km[R]         (normal layout)
//   Vt[((b*8+h)*64+dc)][kk] = (A@Tv^T + bv)[R][C]  (transposed: h=C>>6,
//       dc=C&63, b=R>>10, kk=R&1023; r-index = 4 consecutive kk -> 8B store)
// ---------------------------------------------------------------------------
__global__ __launch_bounds__(256, 2) void gemmKV(
    const float* __restrict__ A, const bf16* __restrict__ Btk,
    const bf16* __restrict__ Btv, const bf16* __restrict__ bk,
    const bf16* __restrict__ bv, const bf16* __restrict__ Km,
    bf16* __restrict__ Kp, bf16* __restrict__ Vt) {
  __shared__ bf16 sA[128 * 32];
  __shared__ bf16 sBk[128 * 32];
  __shared__ bf16 sBv[128 * 32];
  const int tid = threadIdx.x;
  const int lane = tid & 63;
  const int w = tid >> 6;
  const int fm = lane & 15;
  const int fq = lane >> 4;
  const long rowBase = (long)blockIdx.y * 128;
  const int colBase = blockIdx.x * 128;

  f32x4 acck[4][4] = {};
  f32x4 accv[4][4] = {};

  const int c0 = tid, c1 = tid + 256;
  const int r0 = c0 >> 2, o0 = (c0 & 3) * 8;
  const int r1 = c1 >> 2, o1 = (c1 & 3) * 8;
  const float* F0 = A + (rowBase + r0) * 512 + o0;
  const float* F1 = A + (rowBase + r1) * 512 + o1;
  const bf16* Bk0 = Btk + (size_t)(colBase + r0) * 512 + o0;
  const bf16* Bk1 = Btk + (size_t)(colBase + r1) * 512 + o1;
  const bf16* Bv0 = Btv + (size_t)(colBase + r0) * 512 + o0;
  const bf16* Bv1 = Btv + (size_t)(colBase + r1) * 512 + o1;

  const int wr = (w & 1) * 64;
  const int wc = (w >> 1) * 64;

  f32x4 nx0 = *(const f32x4*)(F0);
  f32x4 nx1 = *(const f32x4*)(F0 + 4);
  f32x4 ny0 = *(const f32x4*)(F1);
  f32x4 ny1 = *(const f32x4*)(F1 + 4);

  for (int kt = 0; kt < 16; ++kt) {
    const int k0 = kt * 32;
    __syncthreads();
    {
      bf16x8 p, q;
#pragma unroll
      for (int j = 0; j < 4; ++j) {
        p[j] = (bf16)nx0[j]; p[j + 4] = (bf16)nx1[j];
        q[j] = (bf16)ny0[j]; q[j + 4] = (bf16)ny1[j];
      }
      *(bf16x8*)(sA + c0 * 8) = p;
      *(bf16x8*)(sA + c1 * 8) = q;
      if (kt < 15) {
        nx0 = *(const f32x4*)(F0 + k0 + 32);
        nx1 = *(const f32x4*)(F0 + k0 + 36);
        ny0 = *(const f32x4*)(F1 + k0 + 32);
        ny1 = *(const f32x4*)(F1 + k0 + 36);
      }
    }
    async_lds16(Bk0 + k0, sBk + c0 * 8);
    async_lds16(Bk1 + k0, sBk + c1 * 8);
    async_lds16(Bv0 + k0, sBv + c0 * 8);
    async_lds16(Bv1 + k0, sBv + c1 * 8);
    __syncthreads();
    bf16x8 a[4], b[4], bv2[4];
#pragma unroll
    for (int i = 0; i < 4; ++i)
      a[i] = *(const bf16x8*)(sA + (wr + i * 16 + fm) * 32 + fq * 8);
#pragma unroll
    for (int j = 0; j < 4; ++j) {
      b[j] = *(const bf16x8*)(sBk + (wc + j * 16 + fm) * 32 + fq * 8);
      bv2[j] = *(const bf16x8*)(sBv + (wc + j * 16 + fm) * 32 + fq * 8);
    }
#pragma unroll
    for (int i = 0; i < 4; ++i)
#pragma unroll
      for (int j = 0; j < 4; ++j) {
        acck[i][j] = MFMA16(a[i], b[j], acck[i][j]);
        accv[i][j] = MFMA16(a[i], bv2[j], accv[i][j]);
      }
  }

  const int bidx = (int)(rowBase >> 10);
#pragma unroll
  for (int i = 0; i < 4; ++i) {
#pragma unroll
    for (int r = 0; r < 4; ++r) {
      const long R = rowBase + wr + i * 16 + fq * 4 + r;
      const float mk = (float)Km[R];
      bf16* outrow = Kp + R * 512;
#pragma unroll
      for (int j = 0; j < 4; ++j) {
        const int C = colBase + wc + j * 16 + fm;
        outrow[C] = (bf16)((acck[i][j][r] + (float)bk[C]) * mk);
      }
    }
    // V: transposed store, r -> consecutive kk
    const int kkb = (int)(rowBase & 1023) + wr + i * 16 + fq * 4;
#pragma unroll
    for (int j = 0; j < 4; ++j) {
      const int C = colBase + wc + j * 16 + fm;
      const float bvc = (float)bv[C];
      bf16x4 pv;
#pragma unroll
      for (int r = 0; r < 4; ++r) pv[r] = (bf16)(accv[i][j][r] + bvc);
      bf16* dst = Vt + ((size_t)(bidx * 8 + (C >> 6)) * 64 + (C & 63)) * 1024 + kkb;
      *(bf16x4*)((void*)dst) = pv;
    }
  }
}

// ---------------------------------------------------------------------------
// Attention: linear grid, XCD-swizzled: id%8 == h for all q-tiles of (b,h)
// so one (b,h)'s K/Vt slices stay in one XCD's L2 (16 pairs x 256KB ~ 4MB).
// 4 waves; wave owns 16 q-rows. S^T MFMA -> lane q=fm, kk=fq*4+r.
// y = exp2(exp2(s*c1)*kml); binary Qm factored to epilogue.
// Writes O in-place over Qp.
// ---------------------------------------------------------------------------
__global__ __launch_bounds__(256) void attn_kernel(
    bf16* __restrict__ Qp, const bf16* __restrict__ Kp,
    const bf16* __restrict__ Vt, const bf16* __restrict__ Qm,
    const bf16* __restrict__ Km) {
  __shared__ bf16 sQ[64][72];      // [q][d]
  __shared__ bf16 sK[64][72];      // [kk][d]
  __shared__ bf16 sVt[64][72];     // [d][kk]
  __shared__ bf16 sX[4][16][72];   // per-wave [q][kk]
  __shared__ float sKl[64];        // km * log2e
  __shared__ float sL[4][16];

  const int tid = threadIdx.x;
  const int lane = tid & 63;
  const int w = tid >> 6;
  const int fm = lane & 15;
  const int fq = lane >> 4;
  const int id = blockIdx.x;
  const int bh = id & 127;         // id%8 == bh%8 == h  -> XCD locality
  const int q0 = (id >> 7) * 64;
  const int b = bh >> 3;
  const int hh = bh & 7;

  bf16* Qbase = Qp + ((long)b * 1024 + q0) * 512 + hh * 64;
  for (int c = tid; c < 512; c += 256) {
    const int row = c >> 3, col = (c & 7) * 8;
    *(bf16x8*)(&sQ[row][col]) = *(const bf16x8*)(Qbase + (long)row * 512 + col);
  }
  const float qm_lane = (float)Qm[(long)b * 1024 + q0 + w * 16 + fm];
  __syncthreads();

  // loop-invariant Q fragments (A/B operand layout: row fm, k = ks*32+fq*8)
  bf16x8 qf[2];
  qf[0] = *(const bf16x8*)(&sQ[w * 16 + fm][fq * 8]);
  qf[1] = *(const bf16x8*)(&sQ[w * 16 + fm][32 + fq * 8]);

  f32x4 acc_o[4] = {};
  float l_lane = 0.f;
  const float c1 = 0.063758715f;   // log2(e)/sqrt(512)
  const float LOG2E = 1.4426950408889634f;

  const bf16* Vthead = Vt + ((long)b * 8 + hh) * 64 * 1024;  // [d][kk]
  const bf16* Kbb = Kp + (long)b * 1024 * 512 + hh * 64;
  const bf16* Kmb = Km + (long)b * 1024;

  for (int kt = 0; kt < 16; ++kt) {
    const int kk0 = kt * 64;
    __syncthreads();
    const bf16* Kbase = Kbb + (long)kk0 * 512;
    for (int c = tid; c < 512; c += 256) {
      const int row = c >> 3, col = (c & 7) * 8;
      *(bf16x8*)(&sK[row][col]) = *(const bf16x8*)(Kbase + (long)row * 512 + col);
      *(bf16x8*)(&sVt[row][col]) =
          *(const bf16x8*)(Vthead + (long)row * 1024 + kk0 + col);
    }
    if (tid < 64) sKl[tid] = (float)Kmb[kk0 + tid] * LOG2E;
    __syncthreads();

    // S^T: per wave C[kk 64][q 16]; A = K rows (m=kk), B = Q rows (n=q)
    f32x4 s_acc[4] = {};
#pragma unroll
    for (int ks = 0; ks < 2; ++ks)
#pragma unroll
      for (int t = 0; t < 4; ++t) {
        const bf16x8 kf = *(const bf16x8*)(&sK[t * 16 + fm][ks * 32 + fq * 8]);
        s_acc[t] = MFMA16(kf, qf[ks], s_acc[t]);
      }
    // lane holds q=fm, kk = t*16 + fq*4 + r;  y = exp2(exp2(s*c1)*kml)
#pragma unroll
    for (int t = 0; t < 4; ++t) {
      const f32x4 kml4 = *(const f32x4*)(&sKl[t * 16 + fq * 4]);
      bf16x4 xp;
#pragma unroll
      for (int r = 0; r < 4; ++r) {
        const float e1 = EXP2F(s_acc[t][r] * c1);
        const float y = EXP2F(e1 * kml4[r]);
        l_lane += y;
        xp[r] = (bf16)y;
      }
      *(bf16x4*)((void*)&sX[w][fm][t * 16 + fq * 4]) = xp;  // b64, own wave
    }
    // PV: C[q 16][d 64]; A = sX rows (m=q), B = sVt rows (n=d)
#pragma unroll
    for (int ks = 0; ks < 2; ++ks) {
      const bf16x8 xf = *(const bf16x8*)(&sX[w][fm][ks * 32 + fq * 8]);
#pragma unroll
      for (int t = 0; t < 4; ++t) {
        const bf16x8 vf = *(const bf16x8*)(&sVt[t * 16 + fm][ks * 32 + fq * 8]);
        acc_o[t] = MFMA16(xf, vf, acc_o[t]);
      }
    }
  }

  // per-q Y-sums: lane partial (q=fm) -> total across fq groups
  l_lane += __shfl_xor(l_lane, 16);
  l_lane += __shfl_xor(l_lane, 32);
  if (fq == 0) sL[w][fm] = l_lane;

  // epilogue: lane holds q = fq*4+r, d = fm (PV C-layout)
#pragma unroll
  for (int t = 0; t < 4; ++t) {
#pragma unroll
    for (int r = 0; r < 4; ++r) {
      const int qr = w * 16 + fq * 4 + r;
      const int dc = t * 16 + fm;
      const float qm_r = __shfl(qm_lane, fq * 4 + r, 64);
      const float li = 1.0f / (qm_r * sL[w][fq * 4 + r] + 1e-8f);
      const float val = (float)sQ[qr][dc] + qm_r * acc_o[t][r] * li;
      Qbase[(long)qr * 512 + dc] = (bf16)val;
    }
  }
}

// ---------------------------------------------------------------------------
// LayerNorm (bf16 -> bf16). One wave per row. In-place safe.
// ---------------------------------------------------------------------------
__global__ __launch_bounds__(256) void lnorm(
    const bf16* __restrict__ X, const bf16* __restrict__ g,
    const bf16* __restrict__ bb, bf16* __restrict__ out) {
  const int row = blockIdx.x * 4 + (threadIdx.x >> 6);
  const int lane = threadIdx.x & 63;
  const bf16x8 v = *(const bf16x8*)(X + (size_t)row * 512 + lane * 8);
  float x[8], s = 0.f, ss = 0.f;
#pragma unroll
  for (int j = 0; j < 8; ++j) {
    x[j] = (float)v[j];
    s += x[j];
    ss += x[j] * x[j];
  }
#pragma unroll
  for (int m = 1; m < 64; m <<= 1) {
    s += __shfl_xor(s, m);
    ss += __shfl_xor(ss, m);
  }
  const float mean = s * (1.0f / 512.0f);
  const float var = ss * (1.0f / 512.0f) - mean * mean;
  const float rstd = 1.0f / sqrtf(var + 1e-5f);
  const bf16x8 gv = *(const bf16x8*)(g + lane * 8);
  const bf16x8 bv = *(const bf16x8*)(bb + lane * 8);
  bf16x8 o;
#pragma unroll
  for (int j = 0; j < 8; ++j)
    o[j] = (bf16)((x[j] - mean) * rstd * (float)gv[j] + (float)bv[j]);
  *(bf16x8*)(out + (size_t)row * 512 + lane * 8) = o;
}

// ---------------------------------------------------------------------------
// Final LayerNorm: bf16 in, f32 out.
// ---------------------------------------------------------------------------
__global__ __launch_bounds__(256) void lnorm_out(
    const bf16* __restrict__ X, const bf16* __restrict__ g,
    const bf16* __restrict__ bb, float* __restrict__ out) {
  const int row = blockIdx.x * 4 + (threadIdx.x >> 6);
  const int lane = threadIdx.x & 63;
  const bf16x8 v = *(const bf16x8*)(X + (size_t)row * 512 + lane * 8);
  float x[8], s = 0.f, ss = 0.f;
#pragma unroll
  for (int j = 0; j < 8; ++j) {
    x[j] = (float)v[j];
    s += x[j];
    ss += x[j] * x[j];
  }
#pragma unroll
  for (int m = 1; m < 64; m <<= 1) {
    s += __shfl_xor(s, m);
    ss += __shfl_xor(ss, m);
  }
  const float mean = s * (1.0f / 512.0f);
  const float var = ss * (1.0f / 512.0f) - mean * mean;
  const float rstd = 1.0f / sqrtf(var + 1e-5f);
  const bf16x8 gv = *(const bf16x8*)(g + lane * 8);
  const bf16x8 bv = *(const bf16x8*)(bb + lane * 8);
  f32x4 a, c;
#pragma unroll
  for (int j = 0; j < 4; ++j) {
    a[j] = (x[j] - mean) * rstd * (float)gv[j] + (float)bv[j];
    c[j] = (x[j + 4] - mean) * rstd * (float)gv[j + 4] + (float)bv[j + 4];
  }
  float* fo = out + (size_t)row * 512 + lane * 8;
  *(f32x4*)fo = a;
  *(f32x4*)(fo + 4) = c;
}

// ---------------------------------------------------------------------------
extern "C" void kernel_launch(void* const* d_in, const int* in_sizes, int n_in,
                              void* d_out, int out_size, void* d_ws, size_t ws_size,
                              hipStream_t stream) {
  (void)in_sizes; (void)n_in; (void)out_size; (void)ws_size;
  const float* Q = (const float*)d_in[0];
  const float* K = (const float*)d_in[1];

  bf16* ws = (bf16*)d_ws;
  const long W2 = 512L * 512;
  const long MN = 16384L * 512;
  bf16* Tq = ws;                           // 4 transposed bf16 weights: 2MB
  bf16* Tk = Tq + W2;
  bf16* Tv = Tk + W2;
  bf16* To = Tv + W2;
  bf16* sm = To + W2;                      // 8 x 512 smalls
  bf16* cQm = sm + 8 * 512;                // 16384
  bf16* cKm = cQm + 16384;                 // 16384
  bf16* Qp = cKm + 16384;                  // 16MB
  bf16* Kp = Qp + MN;                      // 16MB
  bf16* Vt = (bf16*)d_out;                 // V^T (bf16) in d_out (dead pre-LN1)

  bf16* cbq = sm + 0 * 512;
  bf16* cbk = sm + 1 * 512;
  bf16* cbv = sm + 2 * 512;
  bf16* cbo = sm + 3 * 512;
  bf16* cg0 = sm + 4 * 512;
  bf16* cb0 = sm + 5 * 512;
  bf16* cg1 = sm + 6 * 512;
  bf16* cb1 = sm + 7 * 512;

  transposeW<<<dim3(8, 8, 4), 256, 0, stream>>>(
      (const float*)d_in[4], (const float*)d_in[6],
      (const float*)d_in[8], (const float*)d_in[10], Tq, Tk, Tv, To);

  ConvArgs ca;
  ca.src[0] = (const float*)d_in[2];  ca.dst[0] = cQm; ca.n[0] = 16384;
  ca.src[1] = (const float*)d_in[3];  ca.dst[1] = cKm; ca.n[1] = 16384;
  ca.src[2] = (const float*)d_in[5];  ca.dst[2] = cbq; ca.n[2] = 512;
  ca.src[3] = (const float*)d_in[7];  ca.dst[3] = cbk; ca.n[3] = 512;
  ca.src[4] = (const float*)d_in[9];  ca.dst[4] = cbv; ca.n[4] = 512;
  ca.src[5] = (const float*)d_in[11]; ca.dst[5] = cbo; ca.n[5] = 512;
  ca.src[6] = (const float*)d_in[12]; ca.dst[6] = cg0; ca.n[6] = 512;
  ca.src[7] = (const float*)d_in[13]; ca.dst[7] = cb0; ca.n[7] = 512;
  ca.src[8] = (const float*)d_in[14]; ca.dst[8] = cg1; ca.n[8] = 512;
  ca.src[9] = (const float*)d_in[15]; ca.dst[9] = cb1; ca.n[9] = 512;
  convert_all<<<dim3(8, 1, 10), 256, 0, stream>>>(ca);

  const dim3 gg(4, 128);
  gemm512<true><<<gg, 256, 0, stream>>>(Q, Tq, cbq, cQm, nullptr, Qp);
  gemmKV<<<gg, 256, 0, stream>>>(K, Tk, Tv, cbk, cbv, cKm, Kp, Vt);

  attn_kernel<<<2048, 256, 0, stream>>>(Qp, Kp, Vt, cQm, cKm);

  lnorm<<<4096, 256, 0, stream>>>(Qp, cg0, cb0, Qp);
  gemm512<false><<<gg, 256, 0, stream>>>(Qp, To, cbo, nullptr, Qp, Kp);
  lnorm_out<<<4096, 256, 0, stream>>>(Kp, cg1, cb1, (float*)d_out);
}

// Round 7
// 293.578 us; speedup vs baseline: 1.2679x; 1.0608x over previous
//
#include <hip/hip_runtime.h>
#include <hip/hip_bf16.h>
#include <cstdint>

// ---------------------------------------------------------------------------
// MAB block (f32 in/out, bf16 internal):
//   Qp=(Q@Wq+bq)*Qm; Kp=(K@Wk+bk)*Km; V=K@Wv+bv
//   S = Qh Kh^T / sqrt(512);  X = exp(exp(S)*Km)*Qm;  A = X/(sum+1e-8)
//   O = Qh + A@Vh;  O = LN0(O);  O = O + relu(O@Wo+bo);  out = LN1(O)
//
// R7: (1) Q,K pre-converted to bf16 once; all GEMMs use the all-async
//     global_load_lds path. GEMM grids XCD-swizzled: 4 col-blocks of a
//     row-block share id&7 -> same XCD -> A row-slice fetched once to L2.
//     (2) attn: 128-q-row blocks, wave owns 32 q-rows (M=32): kf/vf
//     fragments feed 2 MFMAs each -> LDS reads/MFMA 1.125 -> 0.625,
//     staging + K/V fetch per q-row halved. (R6 showed attn LDS-bound:
//     FETCH 139->48MB yet dur 91->87.)
// Buffers: ws ~36MB (T, smalls, masks, Qp, Kp); Qbf borrows Kp slot;
// d_out 32MB: lower=Kbf, upper=Vt (both dead before final LN writes).
// ---------------------------------------------------------------------------

typedef __bf16 bf16;
typedef __bf16 bf16x4 __attribute__((ext_vector_type(4)));
typedef __bf16 bf16x8 __attribute__((ext_vector_type(8)));
typedef float f32x4 __attribute__((ext_vector_type(4)));

#define MFMA16(a, b, c) __builtin_amdgcn_mfma_f32_16x16x32_bf16((a), (b), (c), 0, 0, 0)

#if __has_builtin(__builtin_amdgcn_exp2f)
#define EXP2F(x) __builtin_amdgcn_exp2f(x)
#else
#define EXP2F(x) exp2f(x)
#endif

static __device__ __forceinline__ void async_lds16(const bf16* g, bf16* l) {
  __builtin_amdgcn_global_load_lds(
      (__attribute__((address_space(1))) void*)(void*)g,
      (__attribute__((address_space(3))) void*)l,
      16, 0, 0);
}

// XCD swizzle for 512-block GEMM grids: 4 col-blocks of one row share id&7.
static __device__ __forceinline__ void swz512(int id, long& rowBase, int& colBase) {
  colBase = ((id >> 3) & 3) * 128;
  rowBase = (long)((id & 7) + 8 * (id >> 5)) * 128;
}

// ---------------------------------------------------------------------------
// Weight convert+transpose: T[n][k] = (bf16)W[k][n], 512x512, f32 in.
// ---------------------------------------------------------------------------
__global__ __launch_bounds__(256) void transposeW(
    const float* __restrict__ Wq, const float* __restrict__ Wk,
    const float* __restrict__ Wv, const float* __restrict__ Wo,
    bf16* __restrict__ Tq, bf16* __restrict__ Tk,
    bf16* __restrict__ Tv, bf16* __restrict__ To) {
  const float* src;
  bf16* dst;
  switch (blockIdx.z) {
    case 0: src = Wq; dst = Tq; break;
    case 1: src = Wk; dst = Tk; break;
    case 2: src = Wv; dst = Tv; break;
    default: src = Wo; dst = To; break;
  }
  __shared__ bf16 t[64][72];
  const int tid = threadIdx.x;
  const int n0 = blockIdx.x * 64;
  const int k0 = blockIdx.y * 64;
  for (int c = tid; c < 512; c += 256) {
    const int row = c >> 3, col = (c & 7) * 8;   // row: k, col: n
    const float* sp = src + (size_t)(k0 + row) * 512 + n0 + col;
    const f32x4 a = *(const f32x4*)sp;
    const f32x4 b = *(const f32x4*)(sp + 4);
    bf16x8 v;
#pragma unroll
    for (int j = 0; j < 4; ++j) { v[j] = (bf16)a[j]; v[j + 4] = (bf16)b[j]; }
    *(bf16x8*)(&t[row][col]) = v;
  }
  __syncthreads();
  for (int c = tid; c < 512; c += 256) {
    const int row = c >> 3, col8 = (c & 7) * 8;  // row: n, col8: k
    bf16x8 v;
#pragma unroll
    for (int j = 0; j < 8; ++j) v[j] = t[col8 + j][row];
    *(bf16x8*)(dst + (size_t)(n0 + row) * 512 + k0 + col8) = v;
  }
}

// ---------------------------------------------------------------------------
// Big f32 -> bf16 conversion for Q and K (8.4M elems each; y selects).
// ---------------------------------------------------------------------------
__global__ __launch_bounds__(256) void convertX(
    const float* __restrict__ Q, const float* __restrict__ K,
    bf16* __restrict__ Qb, bf16* __restrict__ Kb) {
  const float* s = blockIdx.y ? K : Q;
  bf16* d = blockIdx.y ? Kb : Qb;
  const long i = ((long)blockIdx.x * 256 + threadIdx.x) * 8;
  const f32x4 x0 = *(const f32x4*)(s + i);
  const f32x4 x1 = *(const f32x4*)(s + i + 4);
  bf16x8 o;
#pragma unroll
  for (int j = 0; j < 4; ++j) { o[j] = (bf16)x0[j]; o[j + 4] = (bf16)x1[j]; }
  *(bf16x8*)(d + i) = o;
}

// ---------------------------------------------------------------------------
// Batched f32->bf16 conversion of 10 small arrays.
// ---------------------------------------------------------------------------
struct ConvArgs {
  const float* src[10];
  bf16* dst[10];
  int n[10];
};

__global__ __launch_bounds__(256) void convert_all(ConvArgs a) {
  const int seg = blockIdx.z;
  const int n = a.n[seg];
  const long i = ((long)blockIdx.x * 256 + threadIdx.x) * 8;
  if (i >= n) return;
  const float* s = a.src[seg];
  const f32x4 x0 = *(const f32x4*)(s + i);
  const f32x4 x1 = *(const f32x4*)(s + i + 4);
  bf16x8 o;
#pragma unroll
  for (int j = 0; j < 4; ++j) { o[j] = (bf16)x0[j]; o[j + 4] = (bf16)x1[j]; }
  *(bf16x8*)(a.dst[seg] + i) = o;
}

// ---------------------------------------------------------------------------
// GEMM (bf16 A): out[M x 512] = epilogue(A @ Bt^T + bias).
//   mask != null : out = (acc+bias) * mask[row]
//   resid != null: out = resid + relu(acc+bias)
// m97 structure; XCD-swizzled linear grid (512 blocks).
// ---------------------------------------------------------------------------
__global__ __launch_bounds__(256, 2) void gemm512(
    const bf16* __restrict__ A, const bf16* __restrict__ Bt,
    const bf16* __restrict__ bias, const bf16* __restrict__ mask,
    const bf16* __restrict__ resid, bf16* __restrict__ out) {
  __shared__ bf16 sA[128 * 32];
  __shared__ bf16 sB[128 * 32];
  const int tid = threadIdx.x;
  const int lane = tid & 63;
  const int w = tid >> 6;
  const int fm = lane & 15;
  const int fq = lane >> 4;
  long rowBase; int colBase;
  swz512(blockIdx.x, rowBase, colBase);

  f32x4 acc[4][4] = {};

  const int c0 = tid, c1 = tid + 256;
  const int r0 = c0 >> 2, o0 = (c0 & 3) * 8;
  const int r1 = c1 >> 2, o1 = (c1 & 3) * 8;
  const bf16* A0 = A + (rowBase + r0) * 512 + o0;
  const bf16* A1 = A + (rowBase + r1) * 512 + o1;
  const bf16* B0 = Bt + (size_t)(colBase + r0) * 512 + o0;
  const bf16* B1 = Bt + (size_t)(colBase + r1) * 512 + o1;

  const int wr = (w & 1) * 64;
  const int wc = (w >> 1) * 64;

  for (int kt = 0; kt < 16; ++kt) {
    const int k0 = kt * 32;
    __syncthreads();
    async_lds16(A0 + k0, sA + c0 * 8);
    async_lds16(A1 + k0, sA + c1 * 8);
    async_lds16(B0 + k0, sB + c0 * 8);
    async_lds16(B1 + k0, sB + c1 * 8);
    __syncthreads();
    bf16x8 a[4], b[4];
#pragma unroll
    for (int i = 0; i < 4; ++i)
      a[i] = *(const bf16x8*)(sA + (wr + i * 16 + fm) * 32 + fq * 8);
#pragma unroll
    for (int j = 0; j < 4; ++j)
      b[j] = *(const bf16x8*)(sB + (wc + j * 16 + fm) * 32 + fq * 8);
#pragma unroll
    for (int i = 0; i < 4; ++i)
#pragma unroll
      for (int j = 0; j < 4; ++j)
        acc[i][j] = MFMA16(a[i], b[j], acc[i][j]);
  }

  // epilogue; C/D layout: col = lane&15, row = (lane>>4)*4 + r
#pragma unroll
  for (int i = 0; i < 4; ++i) {
#pragma unroll
    for (int r = 0; r < 4; ++r) {
      const long R = rowBase + wr + i * 16 + fq * 4 + r;
      const float mk = mask ? (float)mask[R] : 1.0f;
      const bf16* resrow = resid ? resid + R * 512 : nullptr;
      bf16* outrow = out + R * 512;
#pragma unroll
      for (int j = 0; j < 4; ++j) {
        const int C = colBase + wc + j * 16 + fm;
        float v = acc[i][j][r] + (float)bias[C];
        if (mask) v *= mk;
        if (resid) v = (float)resrow[C] + fmaxf(v, 0.0f);
        outrow[C] = (bf16)v;
      }
    }
  }
}

// ---------------------------------------------------------------------------
// Fused K/V projection (bf16 A): one A staging feeds two MFMA chains.
//   Kp[R][C] = (A@Tk^T + bk) * Km[R];  Vt[...] transposed V store.
// ---------------------------------------------------------------------------
__global__ __launch_bounds__(256, 2) void gemmKV(
    const bf16* __restrict__ A, const bf16* __restrict__ Btk,
    const bf16* __restrict__ Btv, const bf16* __restrict__ bk,
    const bf16* __restrict__ bv, const bf16* __restrict__ Km,
    bf16* __restrict__ Kp, bf16* __restrict__ Vt) {
  __shared__ bf16 sA[128 * 32];
  __shared__ bf16 sBk[128 * 32];
  __shared__ bf16 sBv[128 * 32];
  const int tid = threadIdx.x;
  const int lane = tid & 63;
  const int w = tid >> 6;
  const int fm = lane & 15;
  const int fq = lane >> 4;
  long rowBase; int colBase;
  swz512(blockIdx.x, rowBase, colBase);

  f32x4 acck[4][4] = {};
  f32x4 accv[4][4] = {};

  const int c0 = tid, c1 = tid + 256;
  const int r0 = c0 >> 2, o0 = (c0 & 3) * 8;
  const int r1 = c1 >> 2, o1 = (c1 & 3) * 8;
  const bf16* A0 = A + (rowBase + r0) * 512 + o0;
  const bf16* A1 = A + (rowBase + r1) * 512 + o1;
  const bf16* Bk0 = Btk + (size_t)(colBase + r0) * 512 + o0;
  const bf16* Bk1 = Btk + (size_t)(colBase + r1) * 512 + o1;
  const bf16* Bv0 = Btv + (size_t)(colBase + r0) * 512 + o0;
  const bf16* Bv1 = Btv + (size_t)(colBase + r1) * 512 + o1;

  const int wr = (w & 1) * 64;
  const int wc = (w >> 1) * 64;

  for (int kt = 0; kt < 16; ++kt) {
    const int k0 = kt * 32;
    __syncthreads();
    async_lds16(A0 + k0, sA + c0 * 8);
    async_lds16(A1 + k0, sA + c1 * 8);
    async_lds16(Bk0 + k0, sBk + c0 * 8);
    async_lds16(Bk1 + k0, sBk + c1 * 8);
    async_lds16(Bv0 + k0, sBv + c0 * 8);
    async_lds16(Bv1 + k0, sBv + c1 * 8);
    __syncthreads();
    bf16x8 a[4], b[4], bv2[4];
#pragma unroll
    for (int i = 0; i < 4; ++i)
      a[i] = *(const bf16x8*)(sA + (wr + i * 16 + fm) * 32 + fq * 8);
#pragma unroll
    for (int j = 0; j < 4; ++j) {
      b[j] = *(const bf16x8*)(sBk + (wc + j * 16 + fm) * 32 + fq * 8);
      bv2[j] = *(const bf16x8*)(sBv + (wc + j * 16 + fm) * 32 + fq * 8);
    }
#pragma unroll
    for (int i = 0; i < 4; ++i)
#pragma unroll
      for (int j = 0; j < 4; ++j) {
        acck[i][j] = MFMA16(a[i], b[j], acck[i][j]);
        accv[i][j] = MFMA16(a[i], bv2[j], accv[i][j]);
      }
  }

  const int bidx = (int)(rowBase >> 10);
#pragma unroll
  for (int i = 0; i < 4; ++i) {
#pragma unroll
    for (int r = 0; r < 4; ++r) {
      const long R = rowBase + wr + i * 16 + fq * 4 + r;
      const float mk = (float)Km[R];
      bf16* outrow = Kp + R * 512;
#pragma unroll
      for (int j = 0; j < 4; ++j) {
        const int C = colBase + wc + j * 16 + fm;
        outrow[C] = (bf16)((acck[i][j][r] + (float)bk[C]) * mk);
      }
    }
    // V: transposed store, r -> 4 consecutive kk (8B store)
    const int kkb = (int)(rowBase & 1023) + wr + i * 16 + fq * 4;
#pragma unroll
    for (int j = 0; j < 4; ++j) {
      const int C = colBase + wc + j * 16 + fm;
      const float bvc = (float)bv[C];
      bf16x4 pv;
#pragma unroll
      for (int r = 0; r < 4; ++r) pv[r] = (bf16)(accv[i][j][r] + bvc);
      bf16* dst = Vt + ((size_t)(bidx * 8 + (C >> 6)) * 64 + (C & 63)) * 1024 + kkb;
      *(bf16x4*)((void*)dst) = pv;
    }
  }
}

// ---------------------------------------------------------------------------
// Attention: 128-q-row blocks, wave owns 32 q-rows (2 subtiles of 16).
// Grid 1024 linear, XCD-swizzled (id&7==h). S^T MFMA: A=K rows, B=Q rows;
// kf/vf fragments shared across the 2 q-subtiles (halved LDS reads/MFMA).
// y = exp2(exp2(s*c1)*kml); binary Qm factored to epilogue.
// Writes O in-place over Qp (own 128-row tile, staged to sQ first).
// ---------------------------------------------------------------------------
__global__ __launch_bounds__(256, 2) void attn_kernel(
    bf16* __restrict__ Qp, const bf16* __restrict__ Kp,
    const bf16* __restrict__ Vt, const bf16* __restrict__ Qm,
    const bf16* __restrict__ Km) {
  __shared__ bf16 sQ[128][72];     // [q][d]
  __shared__ bf16 sK[64][72];      // [kk][d]
  __shared__ bf16 sVt[64][72];     // [d][kk]
  __shared__ bf16 sX[4][32][72];   // per-wave [q][kk]
  __shared__ float sKl[64];        // km * log2e
  __shared__ float sL[4][32];

  const int tid = threadIdx.x;
  const int lane = tid & 63;
  const int w = tid >> 6;
  const int fm = lane & 15;
  const int fq = lane >> 4;
  const int id = blockIdx.x;
  const int bh = id & 127;         // id%8 == h -> XCD locality for K/V
  const int q0 = (id >> 7) * 128;
  const int b = bh >> 3;
  const int hh = bh & 7;

  bf16* Qbase = Qp + ((long)b * 1024 + q0) * 512 + hh * 64;
  for (int c = tid; c < 1024; c += 256) {
    const int row = c >> 3, col = (c & 7) * 8;
    *(bf16x8*)(&sQ[row][col]) = *(const bf16x8*)(Qbase + (long)row * 512 + col);
  }
  float qm_lane[2];
  qm_lane[0] = (float)Qm[(long)b * 1024 + q0 + w * 32 + fm];
  qm_lane[1] = (float)Qm[(long)b * 1024 + q0 + w * 32 + 16 + fm];
  __syncthreads();

  // loop-invariant Q fragments: [subtile u][ks]
  bf16x8 qf[2][2];
#pragma unroll
  for (int u = 0; u < 2; ++u)
#pragma unroll
    for (int ks = 0; ks < 2; ++ks)
      qf[u][ks] = *(const bf16x8*)(&sQ[w * 32 + u * 16 + fm][ks * 32 + fq * 8]);

  f32x4 acc_o[2][4] = {};
  float l_lane[2] = {0.f, 0.f};
  const float c1 = 0.063758715f;   // log2(e)/sqrt(512)
  const float LOG2E = 1.4426950408889634f;

  const bf16* Vthead = Vt + ((long)b * 8 + hh) * 64 * 1024;  // [d][kk]
  const bf16* Kbb = Kp + (long)b * 1024 * 512 + hh * 64;
  const bf16* Kmb = Km + (long)b * 1024;

  for (int kt = 0; kt < 16; ++kt) {
    const int kk0 = kt * 64;
    __syncthreads();
    const bf16* Kbase = Kbb + (long)kk0 * 512;
    for (int c = tid; c < 512; c += 256) {
      const int row = c >> 3, col = (c & 7) * 8;
      *(bf16x8*)(&sK[row][col]) = *(const bf16x8*)(Kbase + (long)row * 512 + col);
      *(bf16x8*)(&sVt[row][col]) =
          *(const bf16x8*)(Vthead + (long)row * 1024 + kk0 + col);
    }
    if (tid < 64) sKl[tid] = (float)Kmb[kk0 + tid] * LOG2E;
    __syncthreads();

    // S^T: C[kk 64][q 32]; A = K rows (m=kk), B = Q rows (n=q, 2 subtiles)
    f32x4 s_acc[2][4] = {};
#pragma unroll
    for (int ks = 0; ks < 2; ++ks)
#pragma unroll
      for (int t = 0; t < 4; ++t) {
        const bf16x8 kf = *(const bf16x8*)(&sK[t * 16 + fm][ks * 32 + fq * 8]);
        s_acc[0][t] = MFMA16(kf, qf[0][ks], s_acc[0][t]);
        s_acc[1][t] = MFMA16(kf, qf[1][ks], s_acc[1][t]);
      }
    // lane holds q=fm (subtile u), kk = t*16 + fq*4 + r
#pragma unroll
    for (int u = 0; u < 2; ++u)
#pragma unroll
      for (int t = 0; t < 4; ++t) {
        const f32x4 kml4 = *(const f32x4*)(&sKl[t * 16 + fq * 4]);
        bf16x4 xp;
#pragma unroll
        for (int r = 0; r < 4; ++r) {
          const float e1 = EXP2F(s_acc[u][t][r] * c1);
          const float y = EXP2F(e1 * kml4[r]);
          l_lane[u] += y;
          xp[r] = (bf16)y;
        }
        *(bf16x4*)((void*)&sX[w][u * 16 + fm][t * 16 + fq * 4]) = xp;
      }
    // PV: C[q 32][d 64]; A = sX rows (2 subtiles), B = sVt rows (shared)
#pragma unroll
    for (int ks = 0; ks < 2; ++ks) {
      const bf16x8 xf0 = *(const bf16x8*)(&sX[w][fm][ks * 32 + fq * 8]);
      const bf16x8 xf1 = *(const bf16x8*)(&sX[w][16 + fm][ks * 32 + fq * 8]);
#pragma unroll
      for (int t = 0; t < 4; ++t) {
        const bf16x8 vf = *(const bf16x8*)(&sVt[t * 16 + fm][ks * 32 + fq * 8]);
        acc_o[0][t] = MFMA16(xf0, vf, acc_o[0][t]);
        acc_o[1][t] = MFMA16(xf1, vf, acc_o[1][t]);
      }
    }
  }

  // per-q Y-sums
#pragma unroll
  for (int u = 0; u < 2; ++u) {
    l_lane[u] += __shfl_xor(l_lane[u], 16);
    l_lane[u] += __shfl_xor(l_lane[u], 32);
    if (fq == 0) sL[w][u * 16 + fm] = l_lane[u];
  }

  // epilogue: lane holds q = u*16 + fq*4 + r, d = t*16 + fm (PV C-layout)
#pragma unroll
  for (int u = 0; u < 2; ++u) {
#pragma unroll
    for (int t = 0; t < 4; ++t) {
#pragma unroll
      for (int r = 0; r < 4; ++r) {
        const int qr = w * 32 + u * 16 + fq * 4 + r;
        const int dc = t * 16 + fm;
        const float qm_r = __shfl(qm_lane[u], fq * 4 + r, 64);
        const float li = 1.0f / (qm_r * sL[w][u * 16 + fq * 4 + r] + 1e-8f);
        const float val = (float)sQ[qr][dc] + qm_r * acc_o[u][t][r] * li;
        Qbase[(long)qr * 512 + dc] = (bf16)val;
      }
    }
  }
}

// ---------------------------------------------------------------------------
// LayerNorm (bf16 -> bf16). One wave per row. In-place safe.
// ---------------------------------------------------------------------------
__global__ __launch_bounds__(256) void lnorm(
    const bf16* __restrict__ X, const bf16* __restrict__ g,
    const bf16* __restrict__ bb, bf16* __restrict__ out) {
  const int row = blockIdx.x * 4 + (threadIdx.x >> 6);
  const int lane = threadIdx.x & 63;
  const bf16x8 v = *(const bf16x8*)(X + (size_t)row * 512 + lane * 8);
  float x[8], s = 0.f, ss = 0.f;
#pragma unroll
  for (int j = 0; j < 8; ++j) {
    x[j] = (float)v[j];
    s += x[j];
    ss += x[j] * x[j];
  }
#pragma unroll
  for (int m = 1; m < 64; m <<= 1) {
    s += __shfl_xor(s, m);
    ss += __shfl_xor(ss, m);
  }
  const float mean = s * (1.0f / 512.0f);
  const float var = ss * (1.0f / 512.0f) - mean * mean;
  const float rstd = 1.0f / sqrtf(var + 1e-5f);
  const bf16x8 gv = *(const bf16x8*)(g + lane * 8);
  const bf16x8 bv = *(const bf16x8*)(bb + lane * 8);
  bf16x8 o;
#pragma unroll
  for (int j = 0; j < 8; ++j)
    o[j] = (bf16)((x[j] - mean) * rstd * (float)gv[j] + (float)bv[j]);
  *(bf16x8*)(out + (size_t)row * 512 + lane * 8) = o;
}

// ---------------------------------------------------------------------------
// Final LayerNorm: bf16 in, f32 out.
// ---------------------------------------------------------------------------
__global__ __launch_bounds__(256) void lnorm_out(
    const bf16* __restrict__ X, const bf16* __restrict__ g,
    const bf16* __restrict__ bb, float* __restrict__ out) {
  const int row = blockIdx.x * 4 + (threadIdx.x >> 6);
  const int lane = threadIdx.x & 63;
  const bf16x8 v = *(const bf16x8*)(X + (size_t)row * 512 + lane * 8);
  float x[8], s = 0.f, ss = 0.f;
#pragma unroll
  for (int j = 0; j < 8; ++j) {
    x[j] = (float)v[j];
    s += x[j];
    ss += x[j] * x[j];
  }
#pragma unroll
  for (int m = 1; m < 64; m <<= 1) {
    s += __shfl_xor(s, m);
    ss += __shfl_xor(ss, m);
  }
  const float mean = s * (1.0f / 512.0f);
  const float var = ss * (1.0f / 512.0f) - mean * mean;
  const float rstd = 1.0f / sqrtf(var + 1e-5f);
  const bf16x8 gv = *(const bf16x8*)(g + lane * 8);
  const bf16x8 bv = *(const bf16x8*)(bb + lane * 8);
  f32x4 a, c;
#pragma unroll
  for (int j = 0; j < 4; ++j) {
    a[j] = (x[j] - mean) * rstd * (float)gv[j] + (float)bv[j];
    c[j] = (x[j + 4] - mean) * rstd * (float)gv[j + 4] + (float)bv[j + 4];
  }
  float* fo = out + (size_t)row * 512 + lane * 8;
  *(f32x4*)fo = a;
  *(f32x4*)(fo + 4) = c;
}

// ---------------------------------------------------------------------------
extern "C" void kernel_launch(void* const* d_in, const int* in_sizes, int n_in,
                              void* d_out, int out_size, void* d_ws, size_t ws_size,
                              hipStream_t stream) {
  (void)in_sizes; (void)n_in; (void)out_size; (void)ws_size;
  const float* Q = (const float*)d_in[0];
  const float* K = (const float*)d_in[1];

  bf16* ws = (bf16*)d_ws;
  const long W2 = 512L * 512;
  const long MN = 16384L * 512;
  bf16* Tq = ws;                           // 4 transposed bf16 weights: 2MB
  bf16* Tk = Tq + W2;
  bf16* Tv = Tk + W2;
  bf16* To = Tv + W2;
  bf16* sm = To + W2;                      // 8 x 512 smalls
  bf16* cQm = sm + 8 * 512;                // 16384
  bf16* cKm = cQm + 16384;                 // 16384
  bf16* Qp = cKm + 16384;                  // 16MB
  bf16* Kp = Qp + MN;                      // 16MB; Qbf borrows this pre-gemmKV
  bf16* Qbf = Kp;                          // Q bf16 (dead after Q-gemm)
  bf16* Kbf = (bf16*)d_out;                // K bf16 in d_out lower 16MB
  bf16* Vt = (bf16*)d_out + MN;            // V^T in d_out upper 16MB

  bf16* cbq = sm + 0 * 512;
  bf16* cbk = sm + 1 * 512;
  bf16* cbv = sm + 2 * 512;
  bf16* cbo = sm + 3 * 512;
  bf16* cg0 = sm + 4 * 512;
  bf16* cb0 = sm + 5 * 512;
  bf16* cg1 = sm + 6 * 512;
  bf16* cb1 = sm + 7 * 512;

  transposeW<<<dim3(8, 8, 4), 256, 0, stream>>>(
      (const float*)d_in[4], (const float*)d_in[6],
      (const float*)d_in[8], (const float*)d_in[10], Tq, Tk, Tv, To);

  ConvArgs ca;
  ca.src[0] = (const float*)d_in[2];  ca.dst[0] = cQm; ca.n[0] = 16384;
  ca.src[1] = (const float*)d_in[3];  ca.dst[1] = cKm; ca.n[1] = 16384;
  ca.src[2] = (const float*)d_in[5];  ca.dst[2] = cbq; ca.n[2] = 512;
  ca.src[3] = (const float*)d_in[7];  ca.dst[3] = cbk; ca.n[3] = 512;
  ca.src[4] = (const float*)d_in[9];  ca.dst[4] = cbv; ca.n[4] = 512;
  ca.src[5] = (const float*)d_in[11]; ca.dst[5] = cbo; ca.n[5] = 512;
  ca.src[6] = (const float*)d_in[12]; ca.dst[6] = cg0; ca.n[6] = 512;
  ca.src[7] = (const float*)d_in[13]; ca.dst[7] = cb0; ca.n[7] = 512;
  ca.src[8] = (const float*)d_in[14]; ca.dst[8] = cg1; ca.n[8] = 512;
  ca.src[9] = (const float*)d_in[15]; ca.dst[9] = cb1; ca.n[9] = 512;
  convert_all<<<dim3(8, 1, 10), 256, 0, stream>>>(ca);

  convertX<<<dim3(4096, 2), 256, 0, stream>>>(Q, K, Qbf, Kbf);

  gemm512<<<512, 256, 0, stream>>>(Qbf, Tq, cbq, cQm, nullptr, Qp);
  gemmKV<<<512, 256, 0, stream>>>(Kbf, Tk, Tv, cbk, cbv, cKm, Kp, Vt);

  attn_kernel<<<1024, 256, 0, stream>>>(Qp, Kp, Vt, cQm, cKm);

  lnorm<<<4096, 256, 0, stream>>>(Qp, cg0, cb0, Qp);
  gemm512<<<512, 256, 0, stream>>>(Qp, To, cbo, nullptr, Qp, Kp);
  lnorm_out<<<4096, 256, 0, stream>>>(Kp, cg1, cb1, (float*)d_out);
}